// Round 4
// baseline (445.134 us; speedup 1.0000x reference)
//
#include <hip/hip_runtime.h>
#include <cstdint>

#define IN_C 128
#define HID 32
#define HEADS 4
#define OUT_C 16
#define NGRAPH 128
#define NEG 0.2f
#define NB_MAX 256      // buckets of 512 dst nodes; N=100K -> 196 buckets

typedef unsigned int uint;
typedef unsigned short ushort;

__device__ __forceinline__ ushort f2bf(float f) {
  uint u = __float_as_uint(f);
  uint r = (u + 0x7FFF + ((u >> 16) & 1)) >> 16;   // RNE
  return (ushort)r;
}
__device__ __forceinline__ float bflo(uint p) { return __uint_as_float(p << 16); }
__device__ __forceinline__ float bfhi(uint p) { return __uint_as_float(p & 0xFFFF0000u); }

__device__ __forceinline__ int wave_incl_scan_i(int v) {
  int lane = threadIdx.x & 63;
#pragma unroll
  for (int off = 1; off < 64; off <<= 1) {
    int u = __shfl_up(v, off, 64);
    if (lane >= off) v += u;
  }
  return v;
}

// ---------------- binned CSR build (bucket = dst >> 9) ----------------
__global__ void k_bhist(const int* __restrict__ ei, int E, int Etot, int NB,
                        int* __restrict__ bcnt) {
  __shared__ int h[NB_MAX];
  int t = threadIdx.x;
  for (int b = t; b < NB; b += 256) h[b] = 0;
  __syncthreads();
  int base = blockIdx.x * 4096;
  int end = min(base + 4096, Etot);
  for (int e = base + t; e < end; e += 256) {
    int d = (e < E) ? ei[E + e] : (e - E);
    atomicAdd(&h[d >> 9], 1);
  }
  __syncthreads();
  for (int b = t; b < NB; b += 256) if (h[b]) atomicAdd(&bcnt[b], h[b]);
}

__global__ void k_bscan(const int* __restrict__ bcnt, int NB,
                        int* __restrict__ bstart, int Etot,
                        int* __restrict__ offs, int N) {
  if (threadIdx.x == 0) {
    int run = 0;
    for (int b = 0; b < NB; b++) { bstart[b] = run; run += bcnt[b]; }
    bstart[NB] = run;
    offs[N] = Etot;
  }
}

__global__ void k_bin(const int* __restrict__ ei, int E, int Etot, int NB,
                      const int* __restrict__ bstart, int* __restrict__ bcur,
                      uint* __restrict__ bbuf) {
  __shared__ int h[NB_MAX];
  __shared__ int baseo[NB_MAX];
  int t = threadIdx.x;
  for (int b = t; b < NB; b += 256) h[b] = 0;
  __syncthreads();
  int cbase = blockIdx.x * 4096;
  int cend = min(cbase + 4096, Etot);
  for (int e = cbase + t; e < cend; e += 256) {
    int d = (e < E) ? ei[E + e] : (e - E);
    atomicAdd(&h[d >> 9], 1);
  }
  __syncthreads();
  for (int b = t; b < NB; b += 256) {
    int c = h[b];
    baseo[b] = c ? atomicAdd(&bcur[b], c) : 0;
    h[b] = 0;
  }
  __syncthreads();
  for (int e = cbase + t; e < cend; e += 256) {
    int s, d;
    if (e < E) { s = ei[e]; d = ei[E + e]; } else { s = e - E; d = s; }
    int b = d >> 9;
    int r = atomicAdd(&h[b], 1);
    bbuf[bstart[b] + baseo[b] + r] = ((uint)(d & 511) << 17) | (uint)s;
  }
}

// one block (512 thr) per bucket: degrees -> local scan -> offs; rank+scatter in LDS
__global__ void k_build(const uint* __restrict__ bbuf, const int* __restrict__ bstart,
                        int N, int* __restrict__ offs, int* __restrict__ ssrc,
                        int* __restrict__ sdst) {
  __shared__ int deg[512];
  __shared__ int wsum[8];
  int b = blockIdx.x;
  int t = threadIdx.x;
  int lane = t & 63, wid = t >> 6;
  deg[t] = 0;
  __syncthreads();
  int ebeg = bstart[b], eend = bstart[b + 1];
  for (int i = ebeg + t; i < eend; i += 512)
    atomicAdd(&deg[bbuf[i] >> 17], 1);
  __syncthreads();
  int v = deg[t];
  int sv = wave_incl_scan_i(v);
  if (lane == 63) wsum[wid] = sv;
  __syncthreads();
  if (t == 0) {
    int r = 0;
#pragma unroll
    for (int k = 0; k < 8; k++) { int x = wsum[k]; wsum[k] = r; r += x; }
  }
  __syncthreads();
  int excl = wsum[wid] + sv - v;
  int node = (b << 9) + t;
  if (node < N) offs[node] = ebeg + excl;
  __syncthreads();
  deg[t] = excl;                     // becomes local cursor
  __syncthreads();
  for (int i = ebeg + t; i < eend; i += 512) {
    uint rec = bbuf[i];
    int dl = rec >> 17;
    int r = atomicAdd(&deg[dl], 1);
    int pos = ebeg + r;
    ssrc[pos] = (int)(rec & 0x1FFFF);
    sdst[pos] = (b << 9) + dl;
  }
}

// ---------------- GEMM1: hb1[M,128](bf16) = (nw.x)[M,128] @ W1[128,128] ----------------
// BM=64, BN=128 (full), BK=16, 256 thr, 4 rows x (4+4 split cols)/thread.
__global__ void k_gemm1(const float* __restrict__ A, const float* __restrict__ B,
                        const float* __restrict__ rowscale, ushort* __restrict__ Cb,
                        int M) {
  const int BM = 64, BK = 16;
  __shared__ float As[BK][BM + 4];
  __shared__ float Bs[BK][128 + 4];
  const int tid = threadIdx.x;
  const int tx = tid & 15;          // cols tx*4 and tx*4+64
  const int ty = tid >> 4;          // rows ty*4
  const int row0 = blockIdx.x * BM;
  float acc[4][8] = {};
  for (int k0 = 0; k0 < 128; k0 += BK) {
    // A stage: one float4 per thread, transposed into As
    {
      int m = tid >> 2;
      int r = row0 + m;
      int kq = (tid & 3) * 4;
      float4 a4 = make_float4(0.f, 0.f, 0.f, 0.f);
      if (r < M) {
        a4 = *reinterpret_cast<const float4*>(A + (size_t)r * 128 + k0 + kq);
        float sc = rowscale[r];
        a4.x *= sc; a4.y *= sc; a4.z *= sc; a4.w *= sc;
      }
      As[kq][m] = a4.x; As[kq + 1][m] = a4.y; As[kq + 2][m] = a4.z; As[kq + 3][m] = a4.w;
    }
    // B stage: two float4 per thread
#pragma unroll
    for (int q = 0; q < 2; q++) {
      int slot = tid + q * 256;
      int kk = slot >> 5;
      int c4 = (slot & 31) * 4;
      *reinterpret_cast<float4*>(&Bs[kk][c4]) =
          *reinterpret_cast<const float4*>(B + (size_t)(k0 + kk) * 128 + c4);
    }
    __syncthreads();
#pragma unroll
    for (int kk = 0; kk < BK; kk++) {
      float4 a4 = *reinterpret_cast<const float4*>(&As[kk][ty * 4]);
      float4 b0 = *reinterpret_cast<const float4*>(&Bs[kk][tx * 4]);
      float4 b1 = *reinterpret_cast<const float4*>(&Bs[kk][tx * 4 + 64]);
      float av[4] = {a4.x, a4.y, a4.z, a4.w};
      float bv[8] = {b0.x, b0.y, b0.z, b0.w, b1.x, b1.y, b1.z, b1.w};
#pragma unroll
      for (int i = 0; i < 4; i++)
#pragma unroll
        for (int j = 0; j < 8; j++)
          acc[i][j] += av[i] * bv[j];
    }
    __syncthreads();
  }
#pragma unroll
  for (int i = 0; i < 4; i++) {
    int r = row0 + ty * 4 + i;
    if (r < M) {
      ushort4 o0, o1;
      o0.x = f2bf(acc[i][0]); o0.y = f2bf(acc[i][1]);
      o0.z = f2bf(acc[i][2]); o0.w = f2bf(acc[i][3]);
      o1.x = f2bf(acc[i][4]); o1.y = f2bf(acc[i][5]);
      o1.z = f2bf(acc[i][6]); o1.w = f2bf(acc[i][7]);
      *reinterpret_cast<ushort4*>(&Cb[(size_t)r * 128 + tx * 4]) = o0;
      *reinterpret_cast<ushort4*>(&Cb[(size_t)r * 128 + tx * 4 + 64]) = o1;
    }
  }
}

// ---------------- GEMM2: hb2[M,32](bf16) = out1b[M,128](bf16) @ W2[128,32] ----------------
__global__ void k_gemm2(const ushort* __restrict__ A, const float* __restrict__ B,
                        ushort* __restrict__ Cb, int M, int K, int Nc) {
  const int BM = 64, BK = 16, BN = 32;
  __shared__ float As[BK][BM + 4];
  __shared__ float Bs[BK][BN];
  const int tid = threadIdx.x;
  const int nth = 128;
  const int tx = tid % (BN / 4);
  const int ty = tid / (BN / 4);
  const int row0 = blockIdx.x * BM;
  float acc[4][4] = {};
  for (int k0 = 0; k0 < K; k0 += BK) {
    for (int idx = tid; idx < BM * BK / 2; idx += nth) {
      int m = idx >> 3;
      int kp = (idx & 7) * 2;
      int r = row0 + m;
      float v0 = 0.f, v1 = 0.f;
      if (r < M) {
        uint p = *reinterpret_cast<const uint*>(A + (size_t)r * K + k0 + kp);
        v0 = bflo(p); v1 = bfhi(p);
      }
      As[kp][m] = v0; As[kp + 1][m] = v1;
    }
    for (int idx = tid; idx < BK * BN; idx += nth) {
      int kk = idx / BN, c = idx % BN;
      Bs[kk][c] = B[(size_t)(k0 + kk) * Nc + c];
    }
    __syncthreads();
#pragma unroll
    for (int kk = 0; kk < BK; kk++) {
      float4 a4 = *reinterpret_cast<const float4*>(&As[kk][ty * 4]);
      float4 b4 = *reinterpret_cast<const float4*>(&Bs[kk][tx * 4]);
      float av[4] = {a4.x, a4.y, a4.z, a4.w};
      float bv[4] = {b4.x, b4.y, b4.z, b4.w};
#pragma unroll
      for (int i = 0; i < 4; i++)
#pragma unroll
        for (int j = 0; j < 4; j++)
          acc[i][j] += av[i] * bv[j];
    }
    __syncthreads();
  }
#pragma unroll
  for (int i = 0; i < 4; i++) {
    int r = row0 + ty * 4 + i;
    if (r < M) {
      ushort4 o;
      o.x = f2bf(acc[i][0]); o.y = f2bf(acc[i][1]);
      o.z = f2bf(acc[i][2]); o.w = f2bf(acc[i][3]);
      *reinterpret_cast<ushort4*>(&Cb[(size_t)r * Nc + tx * 4]) = o;
    }
  }
}

// ---------------- attention scores ----------------
__global__ void k_att1(const ushort* __restrict__ hb, const float* __restrict__ att_s,
                       const float* __restrict__ att_d, float* __restrict__ o_s,
                       float* __restrict__ o_d, int N) {
  int wid = threadIdx.x >> 6, lane = threadIdx.x & 63;
  int n = blockIdx.x * 4 + wid;
  if (n >= N) return;
  int h = lane >> 4;
  int ch = (2 * lane) & 31;
  uint p = *reinterpret_cast<const uint*>(hb + (size_t)n * 128 + 2 * lane);
  float v0 = bflo(p), v1 = bfhi(p);
  float sa = v0 * att_s[h * 32 + ch] + v1 * att_s[h * 32 + ch + 1];
  float da = v0 * att_d[h * 32 + ch] + v1 * att_d[h * 32 + ch + 1];
#pragma unroll
  for (int off = 8; off > 0; off >>= 1) {
    sa += __shfl_xor(sa, off, 16);
    da += __shfl_xor(da, off, 16);
  }
  if ((lane & 15) == 0) { o_s[n * 4 + h] = sa; o_d[n * 4 + h] = da; }
}

__global__ void k_att2(const ushort* __restrict__ hb, const float* __restrict__ att_s,
                       const float* __restrict__ att_d, float* __restrict__ o_s,
                       float* __restrict__ o_d, int N) {
  int grp = threadIdx.x >> 4, l = threadIdx.x & 15;
  int n = blockIdx.x * 16 + grp;
  if (n >= N) return;
  uint p = *reinterpret_cast<const uint*>(hb + (size_t)n * 32 + 2 * l);
  float v0 = bflo(p), v1 = bfhi(p);
  float sa = v0 * att_s[2 * l] + v1 * att_s[2 * l + 1];
  float da = v0 * att_d[2 * l] + v1 * att_d[2 * l + 1];
#pragma unroll
  for (int off = 8; off > 0; off >>= 1) {
    sa += __shfl_xor(sa, off, 16);
    da += __shfl_xor(da, off, 16);
  }
  if (l == 0) { o_s[n] = sa; o_d[n] = da; }
}

// ---------------- edge softmax weights (unnormalized), CSR-ordered ----------------
__global__ void k_ew1(const int* __restrict__ ssrc, const int* __restrict__ sdst,
                      const float* __restrict__ asrc, const float* __restrict__ adst,
                      float* __restrict__ ew, int M4) {
  int t = blockIdx.x * 256 + threadIdx.x;
  if (t >= M4) return;
  int i = t >> 2, h = t & 3;
  int s = ssrc[i], d = sdst[i];
  float e = asrc[s * 4 + h] + adst[d * 4 + h];
  e = e > 0.f ? e : NEG * e;
  ew[t] = __expf(e);
}

__global__ void k_ew2(const int* __restrict__ ssrc, const int* __restrict__ sdst,
                      const float* __restrict__ asrc, const float* __restrict__ adst,
                      float* __restrict__ ew, int M) {
  int t = blockIdx.x * 256 + threadIdx.x;
  if (t >= M) return;
  int s = ssrc[t], d = sdst[t];
  float e = asrc[s] + adst[d];
  e = e > 0.f ? e : NEG * e;
  ew[t] = __expf(e);
}

// ---------------- layer-1 aggregation: wave per dst, precomputed weights ----------------
__global__ void k_aggr1(const int* __restrict__ offs, const int* __restrict__ ssrc,
                        const float* __restrict__ ew, const ushort* __restrict__ hb,
                        const float* __restrict__ bias, ushort* __restrict__ outb, int N) {
  int wid = threadIdx.x >> 6;
  int lane = threadIdx.x & 63;
  int d = blockIdx.x * 4 + wid;
  if (d >= N) return;
  int h = lane >> 4;
  int beg = offs[d], end = offs[d + 1];
  float ax = 0.f, ay = 0.f, ds = 0.f;
  int i = beg;
  for (; i + 8 <= end; i += 8) {
    int s[8]; float w[8]; uint p[8];
#pragma unroll
    for (int j = 0; j < 8; j++) s[j] = ssrc[i + j];
#pragma unroll
    for (int j = 0; j < 8; j++) w[j] = ew[(i + j) * 4 + h];
#pragma unroll
    for (int j = 0; j < 8; j++) p[j] = *reinterpret_cast<const uint*>(hb + (size_t)s[j] * 128 + 2 * lane);
#pragma unroll
    for (int j = 0; j < 8; j++) {
      ax += w[j] * bflo(p[j]); ay += w[j] * bfhi(p[j]); ds += w[j];
    }
  }
  for (; i < end; i++) {
    int s = ssrc[i];
    float w = ew[i * 4 + h];
    uint p = *reinterpret_cast<const uint*>(hb + (size_t)s * 128 + 2 * lane);
    ax += w * bflo(p); ay += w * bfhi(p); ds += w;
  }
  float inv = 1.f / ds;
  float rx = ax * inv + bias[2 * lane];
  float ry = ay * inv + bias[2 * lane + 1];
  rx = rx > 0.f ? rx : expm1f(rx);
  ry = ry > 0.f ? ry : expm1f(ry);
  uint pk = (uint)f2bf(rx) | ((uint)f2bf(ry) << 16);
  *reinterpret_cast<uint*>(outb + (size_t)d * 128 + 2 * lane) = pk;
}

// ---------------- layer-2 aggregation: 16 lanes per dst, precomputed weights ----------------
__global__ void k_aggr2(const int* __restrict__ offs, const int* __restrict__ ssrc,
                        const float* __restrict__ ew, const ushort* __restrict__ hb,
                        const float* __restrict__ bias, float* __restrict__ out, int N) {
  int grp = threadIdx.x >> 4;
  int l = threadIdx.x & 15;
  int d = blockIdx.x * 16 + grp;
  if (d >= N) return;
  int beg = offs[d], end = offs[d + 1];
  float ax = 0.f, ay = 0.f, ds = 0.f;
  int i = beg;
  for (; i + 8 <= end; i += 8) {
    int s[8]; float w[8]; uint p[8];
#pragma unroll
    for (int j = 0; j < 8; j++) s[j] = ssrc[i + j];
#pragma unroll
    for (int j = 0; j < 8; j++) w[j] = ew[i + j];
#pragma unroll
    for (int j = 0; j < 8; j++) p[j] = *reinterpret_cast<const uint*>(hb + (size_t)s[j] * 32 + 2 * l);
#pragma unroll
    for (int j = 0; j < 8; j++) {
      ax += w[j] * bflo(p[j]); ay += w[j] * bfhi(p[j]); ds += w[j];
    }
  }
  for (; i < end; i++) {
    int s = ssrc[i];
    float w = ew[i];
    uint p = *reinterpret_cast<const uint*>(hb + (size_t)s * 32 + 2 * l);
    ax += w * bflo(p); ay += w * bfhi(p); ds += w;
  }
  float inv = 1.f / ds;
  float rx = ax * inv + bias[2 * l];
  float ry = ay * inv + bias[2 * l + 1];
  rx = rx > 0.f ? rx : expm1f(rx);
  ry = ry > 0.f ? ry : expm1f(ry);
  float2 o = make_float2(rx, ry);
  *reinterpret_cast<float2*>(&out[(size_t)d * 32 + 2 * l]) = o;
}

// ---------------- pool (mean per graph, batch sorted) + FC ----------------
__global__ void k_pool_fc(const float* __restrict__ h2, const int* __restrict__ batch,
                          const float* __restrict__ fcW, const float* __restrict__ fcb,
                          float* __restrict__ out, int N) {
  int g = blockIdx.x;
  int lo = 0, hi = N;
  while (lo < hi) { int mid = (lo + hi) >> 1; if (batch[mid] < g) lo = mid + 1; else hi = mid; }
  int beg = lo;
  hi = N;
  while (lo < hi) { int mid = (lo + hi) >> 1; if (batch[mid] < g + 1) lo = mid + 1; else hi = mid; }
  int end = lo;
  int t = threadIdx.x, c = t & 31, sub = t >> 5;
  float acc = 0.f;
  for (int n = beg + sub; n < end; n += 8) acc += h2[(size_t)n * 32 + c];
  __shared__ float red[8][32];
  __shared__ float pooled[32];
  red[sub][c] = acc;
  __syncthreads();
  if (sub == 0) {
    float s = 0.f;
#pragma unroll
    for (int i = 0; i < 8; i++) s += red[i][c];
    float cnt = (float)(end - beg);
    pooled[c] = s / fmaxf(cnt, 1.f);
  }
  __syncthreads();
  if (t < 16) {
    float r = fcb[t];
#pragma unroll
    for (int cc = 0; cc < 32; cc++) r += pooled[cc] * fcW[cc * 16 + t];
    out[g * 16 + t] = r;
  }
}

// ---------------- host launch ----------------
extern "C" void kernel_launch(void* const* d_in, const int* in_sizes, int n_in,
                              void* d_out, int out_size, void* d_ws, size_t ws_size,
                              hipStream_t stream) {
  const float* x     = (const float*)d_in[0];
  const int*   ei    = (const int*)d_in[1];
  const int*   batch = (const int*)d_in[2];
  const float* nw    = (const float*)d_in[3];
  const float* W1    = (const float*)d_in[4];
  const float* as1w  = (const float*)d_in[5];
  const float* ad1w  = (const float*)d_in[6];
  const float* b1    = (const float*)d_in[7];
  const float* W2    = (const float*)d_in[8];
  const float* as2w  = (const float*)d_in[9];
  const float* ad2w  = (const float*)d_in[10];
  const float* b2    = (const float*)d_in[11];
  const float* fcW   = (const float*)d_in[12];
  const float* fcb   = (const float*)d_in[13];
  float* out = (float*)d_out;

  const int N = in_sizes[0] / IN_C;
  const int E = in_sizes[1] / 2;
  const int Etot = E + N;
  const int NB = (N + 511) >> 9;

  char* w = (char*)d_ws;
  size_t ofs = 0;
  auto alloc = [&](size_t bytes) {
    char* p = w + ofs;
    ofs += (bytes + 255) & ~(size_t)255;
    return p;
  };
  // region 1: hb1 (layer1 features); after aggr1 it is dead -> reused for layer-2 buffers
  char*   reg1   = alloc((size_t)N * 128 * 2);
  ushort* hb1    = (ushort*)reg1;
  ushort* hb2    = (ushort*)reg1;                              // N*32 bf16 (6.4MB)
  float*  asrc2  = (float*)(reg1 + (size_t)N * 32 * 2);        // N fp32
  float*  adst2  = (float*)(reg1 + (size_t)N * 32 * 2 + (size_t)N * 4);
  float*  ew2    = (float*)(reg1 + (size_t)N * 32 * 2 + (size_t)N * 8);  // Etot fp32
  // region 2: out1b (layer1 output); dead after gemm2 -> reused for h2
  char*   reg2   = alloc((size_t)N * 128 * 2);
  ushort* out1b  = (ushort*)reg2;
  float*  h2     = (float*)reg2;                               // N*32 fp32
  // region 3: bbuf (dead after k_build) union ew1 (Etot*4 fp32)
  char*   reg3   = alloc((size_t)Etot * 4 * 4);
  uint*   bbuf   = (uint*)reg3;
  float*  ew1    = (float*)reg3;
  // independent buffers
  float*  asrc1  = (float*)alloc((size_t)N * 4 * 4);
  float*  adst1  = (float*)alloc((size_t)N * 4 * 4);
  int*    bcnt   = (int*)alloc((size_t)(2 * NB) * 4);          // bcnt | bcur
  int*    bcur   = bcnt + NB;
  int*    bstart = (int*)alloc((size_t)(NB + 1) * 4);
  int*    offs   = (int*)alloc((size_t)(N + 1) * 4);
  int*    ssrc   = (int*)alloc((size_t)Etot * 4);
  int*    sdst   = (int*)alloc((size_t)Etot * 4);

  hipMemsetAsync(bcnt, 0, (size_t)(2 * NB) * 4, stream);

  // binned CSR build
  const int nbin = (Etot + 4095) / 4096;
  k_bhist<<<nbin, 256, 0, stream>>>(ei, E, Etot, NB, bcnt);
  k_bscan<<<1, 64, 0, stream>>>(bcnt, NB, bstart, Etot, offs, N);
  k_bin<<<nbin, 256, 0, stream>>>(ei, E, Etot, NB, bstart, bcur, bbuf);
  k_build<<<NB, 512, 0, stream>>>(bbuf, bstart, N, offs, ssrc, sdst);

  // layer 1
  k_gemm1<<<(N + 63) / 64, 256, 0, stream>>>(x, W1, nw, hb1, N);
  k_att1<<<(N + 3) / 4, 256, 0, stream>>>(hb1, as1w, ad1w, asrc1, adst1, N);
  k_ew1<<<(Etot * 4 + 255) / 256, 256, 0, stream>>>(ssrc, sdst, asrc1, adst1, ew1, Etot * 4);
  k_aggr1<<<(N + 3) / 4, 256, 0, stream>>>(offs, ssrc, ew1, hb1, b1, out1b, N);

  // layer 2
  k_gemm2<<<(N + 63) / 64, 128, 0, stream>>>(out1b, W2, hb2, N, 128, 32);
  k_att2<<<(N + 15) / 16, 256, 0, stream>>>(hb2, as2w, ad2w, asrc2, adst2, N);
  k_ew2<<<(Etot + 255) / 256, 256, 0, stream>>>(ssrc, sdst, asrc2, adst2, ew2, Etot);
  k_aggr2<<<(N + 15) / 16, 256, 0, stream>>>(offs, ssrc, ew2, hb2, b2, h2, N);

  // pool + fc
  k_pool_fc<<<NGRAPH, 256, 0, stream>>>(h2, batch, fcW, fcb, out, N);
}

// Round 5
// 432.915 us; speedup vs baseline: 1.0282x; 1.0282x over previous
//
#include <hip/hip_runtime.h>
#include <cstdint>

#define OUT_C 16
#define NGRAPH 128
#define NEG 0.2f
#define NB_MAX 256      // buckets of 512 dst nodes; N=100K -> 196 buckets

typedef unsigned int uint;
typedef unsigned short ushort;
typedef unsigned char uchar;
typedef __attribute__((ext_vector_type(8))) short bf16x8;
typedef __attribute__((ext_vector_type(4))) float f32x4;
typedef __attribute__((ext_vector_type(2))) float f32x2;

union U4B { uint4 u; bf16x8 v; };

__device__ __forceinline__ ushort f2bf(float f) {
  uint u = __float_as_uint(f);
  uint r = (u + 0x7FFF + ((u >> 16) & 1)) >> 16;   // RNE
  return (ushort)r;
}
__device__ __forceinline__ float bflo(uint p) { return __uint_as_float(p << 16); }
__device__ __forceinline__ float bfhi(uint p) { return __uint_as_float(p & 0xFFFF0000u); }

__device__ __forceinline__ int wave_incl_scan_i(int v) {
  int lane = threadIdx.x & 63;
#pragma unroll
  for (int off = 1; off < 64; off <<= 1) {
    int u = __shfl_up(v, off, 64);
    if (lane >= off) v += u;
  }
  return v;
}

// ---------------- binned CSR build (bucket = dst >> 9) ----------------
__global__ void k_bhist(const int* __restrict__ ei, int E, int Etot, int NB,
                        int* __restrict__ bcnt) {
  __shared__ int h[NB_MAX];
  int t = threadIdx.x;
  for (int b = t; b < NB; b += 256) h[b] = 0;
  __syncthreads();
  int base = blockIdx.x * 4096;
  int end = min(base + 4096, Etot);
  for (int e = base + t; e < end; e += 256) {
    int d = (e < E) ? ei[E + e] : (e - E);
    atomicAdd(&h[d >> 9], 1);
  }
  __syncthreads();
  for (int b = t; b < NB; b += 256) if (h[b]) atomicAdd(&bcnt[b], h[b]);
}

__global__ void k_bscan(const int* __restrict__ bcnt, int NB,
                        int* __restrict__ bstart, int Etot,
                        int* __restrict__ offs, int N) {
  if (threadIdx.x == 0) {
    int run = 0;
    for (int b = 0; b < NB; b++) { bstart[b] = run; run += bcnt[b]; }
    bstart[NB] = run;
    offs[N] = Etot;
  }
}

__global__ void k_bin(const int* __restrict__ ei, int E, int Etot, int NB,
                      const int* __restrict__ bstart, int* __restrict__ bcur,
                      uint* __restrict__ bbuf) {
  __shared__ int h[NB_MAX];
  __shared__ int baseo[NB_MAX];
  int t = threadIdx.x;
  for (int b = t; b < NB; b += 256) h[b] = 0;
  __syncthreads();
  int cbase = blockIdx.x * 4096;
  int cend = min(cbase + 4096, Etot);
  for (int e = cbase + t; e < cend; e += 256) {
    int d = (e < E) ? ei[E + e] : (e - E);
    atomicAdd(&h[d >> 9], 1);
  }
  __syncthreads();
  for (int b = t; b < NB; b += 256) {
    int c = h[b];
    baseo[b] = c ? atomicAdd(&bcur[b], c) : 0;
    h[b] = 0;
  }
  __syncthreads();
  for (int e = cbase + t; e < cend; e += 256) {
    int s, d;
    if (e < E) { s = ei[e]; d = ei[E + e]; } else { s = e - E; d = s; }
    int b = d >> 9;
    int r = atomicAdd(&h[b], 1);
    bbuf[bstart[b] + baseo[b] + r] = ((uint)(d & 511) << 17) | (uint)s;
  }
}

// one block (512 thr) per bucket: degrees -> local scan -> offs; rank+scatter in LDS
__global__ void k_build(const uint* __restrict__ bbuf, const int* __restrict__ bstart,
                        int N, int* __restrict__ offs, int* __restrict__ ssrc) {
  __shared__ int deg[512];
  __shared__ int wsum[8];
  int b = blockIdx.x;
  int t = threadIdx.x;
  int lane = t & 63, wid = t >> 6;
  deg[t] = 0;
  __syncthreads();
  int ebeg = bstart[b], eend = bstart[b + 1];
  for (int i = ebeg + t; i < eend; i += 512)
    atomicAdd(&deg[bbuf[i] >> 17], 1);
  __syncthreads();
  int v = deg[t];
  int sv = wave_incl_scan_i(v);
  if (lane == 63) wsum[wid] = sv;
  __syncthreads();
  if (t == 0) {
    int r = 0;
#pragma unroll
    for (int k = 0; k < 8; k++) { int x = wsum[k]; wsum[k] = r; r += x; }
  }
  __syncthreads();
  int excl = wsum[wid] + sv - v;
  int node = (b << 9) + t;
  if (node < N) offs[node] = ebeg + excl;
  __syncthreads();
  deg[t] = excl;                     // becomes local cursor
  __syncthreads();
  for (int i = ebeg + t; i < eend; i += 512) {
    uint rec = bbuf[i];
    int r = atomicAdd(&deg[rec >> 17], 1);
    ssrc[ebeg + r] = (int)(rec & 0x1FFFF);
  }
}

// ---------------- weight prep: Wt1[n][k]=bf16(W1[k][n]), Wt2[n][k]=bf16(W2[k][n]) ----------------
__global__ void k_prep(const float* __restrict__ W1, const float* __restrict__ W2,
                       ushort* __restrict__ Wt1, ushort* __restrict__ Wt2) {
  int t = blockIdx.x * 256 + threadIdx.x;
  if (t < 16384) {
    int n = t >> 7, k = t & 127;
    Wt1[t] = f2bf(W1[k * 128 + n]);
  } else if (t < 16384 + 4096) {
    int u = t - 16384;
    int n = u >> 7, k = u & 127;
    Wt2[u] = f2bf(W2[k * 32 + n]);
  }
}

// ---------------- GEMM1 (MFMA bf16) + fused att1: hb1 fp8[M][128], asrc/adst[M][4] ----------------
// block 256 = 4 waves, each wave: 16 rows x 128 cols, K=128.
__global__ void k_gemm1(const float* __restrict__ x, const ushort* __restrict__ Wt,
                        const float* __restrict__ nw, const float* __restrict__ att_s,
                        const float* __restrict__ att_d, uchar* __restrict__ hb1,
                        float* __restrict__ asrc, float* __restrict__ adst, int M) {
  int wv = threadIdx.x >> 6, l = threadIdx.x & 63;
  int lg = l >> 4, lr = l & 15;
  int row0 = blockIdx.x * 64 + wv * 16;
  int node = row0 + lr;
  bool valid = node < M;
  float sc = valid ? nw[node] : 0.f;
  // A frags: lane holds A[m=lr][k = kc*32 + lg*8 + j]
  bf16x8 afr[4];
  const float* xr = x + (size_t)node * 128;
#pragma unroll
  for (int kc = 0; kc < 4; kc++) {
    float v[8];
    if (valid) {
      float4 q0 = *reinterpret_cast<const float4*>(xr + kc * 32 + lg * 8);
      float4 q1 = *reinterpret_cast<const float4*>(xr + kc * 32 + lg * 8 + 4);
      v[0] = q0.x; v[1] = q0.y; v[2] = q0.z; v[3] = q0.w;
      v[4] = q1.x; v[5] = q1.y; v[6] = q1.z; v[7] = q1.w;
    } else {
#pragma unroll
      for (int j = 0; j < 8; j++) v[j] = 0.f;
    }
    U4B a;
#pragma unroll
    for (int c = 0; c < 4; c++)
      a.u.x = 0, a.u = a.u;  // placeholder no-op to keep union init simple
    uint pk0 = (uint)f2bf(v[0] * sc) | ((uint)f2bf(v[1] * sc) << 16);
    uint pk1 = (uint)f2bf(v[2] * sc) | ((uint)f2bf(v[3] * sc) << 16);
    uint pk2 = (uint)f2bf(v[4] * sc) | ((uint)f2bf(v[5] * sc) << 16);
    uint pk3 = (uint)f2bf(v[6] * sc) | ((uint)f2bf(v[7] * sc) << 16);
    a.u = make_uint4(pk0, pk1, pk2, pk3);
    afr[kc] = a.v;
  }
  float pS[4][4], pD[4][4];
#pragma unroll
  for (int h = 0; h < 4; h++)
#pragma unroll
    for (int v = 0; v < 4; v++) { pS[h][v] = 0.f; pD[h][v] = 0.f; }
#pragma unroll
  for (int ct = 0; ct < 8; ct++) {
    f32x4 acc = {0.f, 0.f, 0.f, 0.f};
    const ushort* wrow = Wt + (size_t)(ct * 16 + lr) * 128;
#pragma unroll
    for (int kc = 0; kc < 4; kc++) {
      U4B bfr;
      bfr.u = *reinterpret_cast<const uint4*>(wrow + kc * 32 + lg * 8);
      acc = __builtin_amdgcn_mfma_f32_16x16x32_bf16(afr[kc], bfr.v, acc, 0, 0, 0);
    }
    int col = ct * 16 + lr;
    float asw = att_s[col], adw = att_d[col];
    int h = ct >> 1;
#pragma unroll
    for (int v = 0; v < 4; v++) {
      int nrow = row0 + lg * 4 + v;
      if (nrow < M) {
        uint b8 = (uint)__builtin_amdgcn_cvt_pk_fp8_f32(acc[v], acc[v], 0, false);
        hb1[(size_t)nrow * 128 + col] = (uchar)(b8 & 0xFF);
      }
      pS[h][v] += acc[v] * asw;
      pD[h][v] += acc[v] * adw;
    }
  }
  // reduce attention partials across the 16 lanes of each lg-group
#pragma unroll
  for (int off = 1; off < 16; off <<= 1) {
#pragma unroll
    for (int h = 0; h < 4; h++)
#pragma unroll
      for (int v = 0; v < 4; v++) {
        pS[h][v] += __shfl_xor(pS[h][v], off, 16);
        pD[h][v] += __shfl_xor(pD[h][v], off, 16);
      }
  }
  if (lr == 0) {
#pragma unroll
    for (int v = 0; v < 4; v++) {
      int n2 = row0 + lg * 4 + v;
      if (n2 < M) {
#pragma unroll
        for (int h = 0; h < 4; h++) {
          asrc[n2 * 4 + h] = pS[h][v];
          adst[n2 * 4 + h] = pD[h][v];
        }
      }
    }
  }
}

// ---------------- GEMM2 (MFMA bf16) + fused att2: hb2 bf16[M][32], asrc2/adst2[M] ----------------
__global__ void k_gemm2(const ushort* __restrict__ A, const ushort* __restrict__ Wt,
                        const float* __restrict__ att_s, const float* __restrict__ att_d,
                        ushort* __restrict__ hb2, float* __restrict__ asrc,
                        float* __restrict__ adst, int M) {
  int wv = threadIdx.x >> 6, l = threadIdx.x & 63;
  int lg = l >> 4, lr = l & 15;
  int row0 = blockIdx.x * 64 + wv * 16;
  int node = row0 + lr;
  bool valid = node < M;
  bf16x8 afr[4];
#pragma unroll
  for (int kc = 0; kc < 4; kc++) {
    U4B a;
    if (valid) a.u = *reinterpret_cast<const uint4*>(A + (size_t)node * 128 + kc * 32 + lg * 8);
    else a.u = make_uint4(0, 0, 0, 0);
    afr[kc] = a.v;
  }
  float pS[4], pD[4];
#pragma unroll
  for (int v = 0; v < 4; v++) { pS[v] = 0.f; pD[v] = 0.f; }
#pragma unroll
  for (int ct = 0; ct < 2; ct++) {
    f32x4 acc = {0.f, 0.f, 0.f, 0.f};
    const ushort* wrow = Wt + (size_t)(ct * 16 + lr) * 128;
#pragma unroll
    for (int kc = 0; kc < 4; kc++) {
      U4B bfr;
      bfr.u = *reinterpret_cast<const uint4*>(wrow + kc * 32 + lg * 8);
      acc = __builtin_amdgcn_mfma_f32_16x16x32_bf16(afr[kc], bfr.v, acc, 0, 0, 0);
    }
    int col = ct * 16 + lr;
    float asw = att_s[col], adw = att_d[col];
#pragma unroll
    for (int v = 0; v < 4; v++) {
      int nrow = row0 + lg * 4 + v;
      if (nrow < M) hb2[(size_t)nrow * 32 + col] = f2bf(acc[v]);
      pS[v] += acc[v] * asw;
      pD[v] += acc[v] * adw;
    }
  }
#pragma unroll
  for (int off = 1; off < 16; off <<= 1) {
#pragma unroll
    for (int v = 0; v < 4; v++) {
      pS[v] += __shfl_xor(pS[v], off, 16);
      pD[v] += __shfl_xor(pD[v], off, 16);
    }
  }
  if (lr == 0) {
#pragma unroll
    for (int v = 0; v < 4; v++) {
      int n2 = row0 + lg * 4 + v;
      if (n2 < M) { asrc[n2] = pS[v]; adst[n2] = pD[v]; }
    }
  }
}

// ---------------- layer-1 aggregation: wave per dst, 8 lanes/edge, 8 edges/iter, fp8 rows ----------------
__global__ void k_aggr1(const int* __restrict__ offs, const int* __restrict__ ssrc,
                        const uchar* __restrict__ hb, const float* __restrict__ asrc,
                        const float* __restrict__ adst, const float* __restrict__ bias,
                        ushort* __restrict__ outb, int N) {
  int wid = threadIdx.x >> 6, l = threadIdx.x & 63;
  int d = blockIdx.x * 4 + wid;
  if (d >= N) return;
  int g = l >> 3;          // edge slot 0..7
  int cl = l & 7;          // channel cluster: ch 16*cl .. +15
  int h = cl >> 1;         // head
  float ad = adst[d * 4 + h];
  int beg = offs[d], end = offs[d + 1];
  float acc[16] = {};
  float ds = 0.f;
  for (int i = beg; i < end; i += 8) {
    int e = i + g;
    int ec = min(e, end - 1);
    int s = ssrc[ec];
    float xv = asrc[s * 4 + h] + ad;
    xv = xv > 0.f ? xv : NEG * xv;
    float w = __expf(xv);
    w = (e < end) ? w : 0.f;
    uint4 p = *reinterpret_cast<const uint4*>(hb + (size_t)s * 128 + cl * 16);
    uint pu[4] = {p.x, p.y, p.z, p.w};
#pragma unroll
    for (int q = 0; q < 4; q++) {
      f32x2 f0 = __builtin_amdgcn_cvt_pk_f32_fp8(pu[q], false);
      f32x2 f1 = __builtin_amdgcn_cvt_pk_f32_fp8(pu[q], true);
      acc[q * 4 + 0] += w * f0.x;
      acc[q * 4 + 1] += w * f0.y;
      acc[q * 4 + 2] += w * f1.x;
      acc[q * 4 + 3] += w * f1.y;
    }
    ds += w;
  }
#pragma unroll
  for (int off = 8; off < 64; off <<= 1) {
    ds += __shfl_xor(ds, off, 64);
#pragma unroll
    for (int k = 0; k < 16; k++) acc[k] += __shfl_xor(acc[k], off, 64);
  }
  if (l < 8) {
    float inv = 1.f / ds;
    uint o[8];
#pragma unroll
    for (int q = 0; q < 8; q++) {
      float r0 = acc[2 * q] * inv + bias[l * 16 + 2 * q];
      float r1 = acc[2 * q + 1] * inv + bias[l * 16 + 2 * q + 1];
      r0 = r0 > 0.f ? r0 : expm1f(r0);
      r1 = r1 > 0.f ? r1 : expm1f(r1);
      o[q] = (uint)f2bf(r0) | ((uint)f2bf(r1) << 16);
    }
    uint4* dst = reinterpret_cast<uint4*>(outb + (size_t)d * 128 + l * 16);
    dst[0] = make_uint4(o[0], o[1], o[2], o[3]);
    dst[1] = make_uint4(o[4], o[5], o[6], o[7]);
  }
}

// ---------------- layer-2 aggregation: wave per dst, 4 lanes/edge, 16 edges/iter, bf16 rows ----------------
__global__ void k_aggr2(const int* __restrict__ offs, const int* __restrict__ ssrc,
                        const ushort* __restrict__ hb, const float* __restrict__ asrc,
                        const float* __restrict__ adst, const float* __restrict__ bias,
                        float* __restrict__ out, int N) {
  int wid = threadIdx.x >> 6, l = threadIdx.x & 63;
  int d = blockIdx.x * 4 + wid;
  if (d >= N) return;
  int g = l >> 2;          // edge slot 0..15
  int cl = l & 3;          // channel cluster: ch 8*cl .. +7
  float ad = adst[d];
  int beg = offs[d], end = offs[d + 1];
  float acc[8] = {};
  float ds = 0.f;
  for (int i = beg; i < end; i += 16) {
    int e = i + g;
    int ec = min(e, end - 1);
    int s = ssrc[ec];
    float xv = asrc[s] + ad;
    xv = xv > 0.f ? xv : NEG * xv;
    float w = __expf(xv);
    w = (e < end) ? w : 0.f;
    uint4 p = *reinterpret_cast<const uint4*>(hb + (size_t)s * 32 + cl * 8);
    uint pu[4] = {p.x, p.y, p.z, p.w};
#pragma unroll
    for (int q = 0; q < 4; q++) {
      acc[2 * q]     += w * bflo(pu[q]);
      acc[2 * q + 1] += w * bfhi(pu[q]);
    }
    ds += w;
  }
#pragma unroll
  for (int off = 4; off < 64; off <<= 1) {
    ds += __shfl_xor(ds, off, 64);
#pragma unroll
    for (int k = 0; k < 8; k++) acc[k] += __shfl_xor(acc[k], off, 64);
  }
  if (l < 4) {
    float inv = 1.f / ds;
    float r[8];
#pragma unroll
    for (int q = 0; q < 8; q++) {
      r[q] = acc[q] * inv + bias[l * 8 + q];
      r[q] = r[q] > 0.f ? r[q] : expm1f(r[q]);
    }
    float4* dst = reinterpret_cast<float4*>(out + (size_t)d * 32 + l * 8);
    dst[0] = make_float4(r[0], r[1], r[2], r[3]);
    dst[1] = make_float4(r[4], r[5], r[6], r[7]);
  }
}

// ---------------- pool (mean per graph, batch sorted) + FC ----------------
__global__ void k_pool_fc(const float* __restrict__ h2, const int* __restrict__ batch,
                          const float* __restrict__ fcW, const float* __restrict__ fcb,
                          float* __restrict__ out, int N) {
  int g = blockIdx.x;
  int lo = 0, hi = N;
  while (lo < hi) { int mid = (lo + hi) >> 1; if (batch[mid] < g) lo = mid + 1; else hi = mid; }
  int beg = lo;
  hi = N;
  while (lo < hi) { int mid = (lo + hi) >> 1; if (batch[mid] < g + 1) lo = mid + 1; else hi = mid; }
  int end = lo;
  int t = threadIdx.x, c = t & 31, sub = t >> 5;
  float acc = 0.f;
  for (int n = beg + sub; n < end; n += 8) acc += h2[(size_t)n * 32 + c];
  __shared__ float red[8][32];
  __shared__ float pooled[32];
  red[sub][c] = acc;
  __syncthreads();
  if (sub == 0) {
    float s = 0.f;
#pragma unroll
    for (int i = 0; i < 8; i++) s += red[i][c];
    float cnt = (float)(end - beg);
    pooled[c] = s / fmaxf(cnt, 1.f);
  }
  __syncthreads();
  if (t < 16) {
    float r = fcb[t];
#pragma unroll
    for (int cc = 0; cc < 32; cc++) r += pooled[cc] * fcW[cc * 16 + t];
    out[g * 16 + t] = r;
  }
}

// ---------------- host launch ----------------
extern "C" void kernel_launch(void* const* d_in, const int* in_sizes, int n_in,
                              void* d_out, int out_size, void* d_ws, size_t ws_size,
                              hipStream_t stream) {
  const float* x     = (const float*)d_in[0];
  const int*   ei    = (const int*)d_in[1];
  const int*   batch = (const int*)d_in[2];
  const float* nw    = (const float*)d_in[3];
  const float* W1    = (const float*)d_in[4];
  const float* as1w  = (const float*)d_in[5];
  const float* ad1w  = (const float*)d_in[6];
  const float* b1    = (const float*)d_in[7];
  const float* W2    = (const float*)d_in[8];
  const float* as2w  = (const float*)d_in[9];
  const float* ad2w  = (const float*)d_in[10];
  const float* b2    = (const float*)d_in[11];
  const float* fcW   = (const float*)d_in[12];
  const float* fcb   = (const float*)d_in[13];
  float* out = (float*)d_out;

  const int N = in_sizes[0] / 128;
  const int E = in_sizes[1] / 2;
  const int Etot = E + N;
  const int NB = (N + 511) >> 9;

  char* w = (char*)d_ws;
  size_t ofs = 0;
  auto alloc = [&](size_t bytes) {
    char* p = w + ofs;
    ofs += (bytes + 255) & ~(size_t)255;
    return p;
  };
  uchar*  hb1    = (uchar*)alloc((size_t)N * 128);        // fp8 layer-1 features
  ushort* out1b  = (ushort*)alloc((size_t)N * 128 * 2);   // bf16 layer-1 output
  ushort* hb2    = (ushort*)alloc((size_t)N * 32 * 2);    // bf16 layer-2 features
  float*  h2     = (float*)alloc((size_t)N * 32 * 4);     // fp32 layer-2 output
  float*  asrc1  = (float*)alloc((size_t)N * 4 * 4);
  float*  adst1  = (float*)alloc((size_t)N * 4 * 4);
  float*  asrc2  = (float*)alloc((size_t)N * 4);
  float*  adst2  = (float*)alloc((size_t)N * 4);
  ushort* Wt1    = (ushort*)alloc(16384 * 2);
  ushort* Wt2    = (ushort*)alloc(4096 * 2);
  int*    bcnt   = (int*)alloc((size_t)(2 * NB) * 4);     // bcnt | bcur
  int*    bcur   = bcnt + NB;
  int*    bstart = (int*)alloc((size_t)(NB + 1) * 4);
  int*    offs   = (int*)alloc((size_t)(N + 1) * 4);
  uint*   bbuf   = (uint*)alloc((size_t)Etot * 4);
  int*    ssrc   = (int*)alloc((size_t)Etot * 4);

  hipMemsetAsync(bcnt, 0, (size_t)(2 * NB) * 4, stream);

  // binned CSR build
  const int nbin = (Etot + 4095) / 4096;
  k_bhist<<<nbin, 256, 0, stream>>>(ei, E, Etot, NB, bcnt);
  k_bscan<<<1, 64, 0, stream>>>(bcnt, NB, bstart, Etot, offs, N);
  k_bin<<<nbin, 256, 0, stream>>>(ei, E, Etot, NB, bstart, bcur, bbuf);
  k_build<<<NB, 512, 0, stream>>>(bbuf, bstart, N, offs, ssrc);

  // weight prep (independent of CSR)
  k_prep<<<80, 256, 0, stream>>>(W1, W2, Wt1, Wt2);

  // layer 1: GEMM+att fused, then aggregation
  k_gemm1<<<(N + 63) / 64, 256, 0, stream>>>(x, Wt1, nw, as1w, ad1w, hb1, asrc1, adst1, N);
  k_aggr1<<<(N + 3) / 4, 256, 0, stream>>>(offs, ssrc, hb1, asrc1, adst1, b1, out1b, N);

  // layer 2
  k_gemm2<<<(N + 63) / 64, 256, 0, stream>>>(out1b, Wt2, as2w, ad2w, hb2, asrc2, adst2, N);
  k_aggr2<<<(N + 3) / 4, 256, 0, stream>>>(offs, ssrc, hb2, asrc2, adst2, b2, h2, N);

  // pool + fc
  k_pool_fc<<<NGRAPH, 256, 0, stream>>>(h2, batch, fcW, fcb, out, N);
}

// Round 6
// 386.093 us; speedup vs baseline: 1.1529x; 1.1213x over previous
//
#include <hip/hip_runtime.h>
#include <cstdint>

#define OUT_C 16
#define NGRAPH 128
#define NEG 0.2f
#define NB_MAX 256      // buckets of 512 dst nodes; N=100K -> 196 buckets

typedef unsigned int uint;
typedef unsigned short ushort;
typedef unsigned char uchar;
typedef __attribute__((ext_vector_type(8))) short bf16x8;
typedef __attribute__((ext_vector_type(4))) float f32x4;
typedef __attribute__((ext_vector_type(2))) float f32x2;

union U4B { uint4 u; bf16x8 v; };

__device__ __forceinline__ ushort f2bf(float f) {
  uint u = __float_as_uint(f);
  uint r = (u + 0x7FFF + ((u >> 16) & 1)) >> 16;   // RNE
  return (ushort)r;
}

__device__ __forceinline__ int wave_incl_scan_i(int v) {
  int lane = threadIdx.x & 63;
#pragma unroll
  for (int off = 1; off < 64; off <<= 1) {
    int u = __shfl_up(v, off, 64);
    if (lane >= off) v += u;
  }
  return v;
}

// ---------------- binned CSR build (bucket = dst >> 9) ----------------
__global__ void k_bhist(const int* __restrict__ ei, int E, int Etot, int NB,
                        int* __restrict__ bcnt) {
  __shared__ int h[NB_MAX];
  int t = threadIdx.x;
  for (int b = t; b < NB; b += 256) h[b] = 0;
  __syncthreads();
  int base = blockIdx.x * 4096;
  int end = min(base + 4096, Etot);
  for (int e = base + t; e < end; e += 256) {
    int d = (e < E) ? ei[E + e] : (e - E);
    atomicAdd(&h[d >> 9], 1);
  }
  __syncthreads();
  for (int b = t; b < NB; b += 256) if (h[b]) atomicAdd(&bcnt[b], h[b]);
}

__global__ void k_bscan(const int* __restrict__ bcnt, int NB,
                        int* __restrict__ bstart, int Etot,
                        int* __restrict__ offs, int N) {
  if (threadIdx.x == 0) {
    int run = 0;
    for (int b = 0; b < NB; b++) { bstart[b] = run; run += bcnt[b]; }
    bstart[NB] = run;
    offs[N] = Etot;
  }
}

__global__ void k_bin(const int* __restrict__ ei, int E, int Etot, int NB,
                      const int* __restrict__ bstart, int* __restrict__ bcur,
                      uint* __restrict__ bbuf) {
  __shared__ int h[NB_MAX];
  __shared__ int baseo[NB_MAX];
  int t = threadIdx.x;
  for (int b = t; b < NB; b += 256) h[b] = 0;
  __syncthreads();
  int cbase = blockIdx.x * 4096;
  int cend = min(cbase + 4096, Etot);
  for (int e = cbase + t; e < cend; e += 256) {
    int d = (e < E) ? ei[E + e] : (e - E);
    atomicAdd(&h[d >> 9], 1);
  }
  __syncthreads();
  for (int b = t; b < NB; b += 256) {
    int c = h[b];
    baseo[b] = c ? atomicAdd(&bcur[b], c) : 0;
    h[b] = 0;
  }
  __syncthreads();
  for (int e = cbase + t; e < cend; e += 256) {
    int s, d;
    if (e < E) { s = ei[e]; d = ei[E + e]; } else { s = e - E; d = s; }
    int b = d >> 9;
    int r = atomicAdd(&h[b], 1);
    bbuf[bstart[b] + baseo[b] + r] = ((uint)(d & 511) << 17) | (uint)s;
  }
}

// one block (512 thr) per bucket: degrees -> local scan -> offs; rank+scatter in LDS
__global__ void k_build(const uint* __restrict__ bbuf, const int* __restrict__ bstart,
                        int N, int* __restrict__ offs, int* __restrict__ ssrc) {
  __shared__ int deg[512];
  __shared__ int wsum[8];
  int b = blockIdx.x;
  int t = threadIdx.x;
  int lane = t & 63, wid = t >> 6;
  deg[t] = 0;
  __syncthreads();
  int ebeg = bstart[b], eend = bstart[b + 1];
  for (int i = ebeg + t; i < eend; i += 512)
    atomicAdd(&deg[bbuf[i] >> 17], 1);
  __syncthreads();
  int v = deg[t];
  int sv = wave_incl_scan_i(v);
  if (lane == 63) wsum[wid] = sv;
  __syncthreads();
  if (t == 0) {
    int r = 0;
#pragma unroll
    for (int k = 0; k < 8; k++) { int x = wsum[k]; wsum[k] = r; r += x; }
  }
  __syncthreads();
  int excl = wsum[wid] + sv - v;
  int node = (b << 9) + t;
  if (node < N) offs[node] = ebeg + excl;
  __syncthreads();
  deg[t] = excl;                     // becomes local cursor
  __syncthreads();
  for (int i = ebeg + t; i < eend; i += 512) {
    uint rec = bbuf[i];
    int r = atomicAdd(&deg[rec >> 17], 1);
    ssrc[ebeg + r] = (int)(rec & 0x1FFFF);
  }
}

// ---------------- weight prep: Wt1[n][k]=bf16(W1[k][n]), Wt2[n][k]=bf16(W2[k][n]) ----------------
__global__ void k_prep(const float* __restrict__ W1, const float* __restrict__ W2,
                       ushort* __restrict__ Wt1, ushort* __restrict__ Wt2) {
  int t = blockIdx.x * 256 + threadIdx.x;
  if (t < 16384) {
    int n = t >> 7, k = t & 127;
    Wt1[t] = f2bf(W1[k * 128 + n]);
  } else if (t < 16384 + 4096) {
    int u = t - 16384;
    int n = u >> 7, k = u & 127;
    Wt2[u] = f2bf(W2[k * 32 + n]);
  }
}

// ---------------- GEMM1 (MFMA bf16) + fused att1: hb1 fp8[M][128], asrc/adst[M][4] ----------------
// block 256 = 4 waves, each wave: 16 rows x 128 cols, K=128.
__global__ void k_gemm1(const float* __restrict__ x, const ushort* __restrict__ Wt,
                        const float* __restrict__ nw, const float* __restrict__ att_s,
                        const float* __restrict__ att_d, uchar* __restrict__ hb1,
                        float* __restrict__ asrc, float* __restrict__ adst, int M) {
  int wv = threadIdx.x >> 6, l = threadIdx.x & 63;
  int lg = l >> 4, lr = l & 15;
  int row0 = blockIdx.x * 64 + wv * 16;
  int node = row0 + lr;
  bool valid = node < M;
  float sc = valid ? nw[node] : 0.f;
  // A frags: lane holds A[m=lr][k = kc*32 + lg*8 + j]
  bf16x8 afr[4];
  const float* xr = x + (size_t)node * 128;
#pragma unroll
  for (int kc = 0; kc < 4; kc++) {
    float v[8];
    if (valid) {
      float4 q0 = *reinterpret_cast<const float4*>(xr + kc * 32 + lg * 8);
      float4 q1 = *reinterpret_cast<const float4*>(xr + kc * 32 + lg * 8 + 4);
      v[0] = q0.x; v[1] = q0.y; v[2] = q0.z; v[3] = q0.w;
      v[4] = q1.x; v[5] = q1.y; v[6] = q1.z; v[7] = q1.w;
    } else {
#pragma unroll
      for (int j = 0; j < 8; j++) v[j] = 0.f;
    }
    U4B a;
    uint pk0 = (uint)f2bf(v[0] * sc) | ((uint)f2bf(v[1] * sc) << 16);
    uint pk1 = (uint)f2bf(v[2] * sc) | ((uint)f2bf(v[3] * sc) << 16);
    uint pk2 = (uint)f2bf(v[4] * sc) | ((uint)f2bf(v[5] * sc) << 16);
    uint pk3 = (uint)f2bf(v[6] * sc) | ((uint)f2bf(v[7] * sc) << 16);
    a.u = make_uint4(pk0, pk1, pk2, pk3);
    afr[kc] = a.v;
  }
  float pS[4][4], pD[4][4];
#pragma unroll
  for (int h = 0; h < 4; h++)
#pragma unroll
    for (int v = 0; v < 4; v++) { pS[h][v] = 0.f; pD[h][v] = 0.f; }
#pragma unroll
  for (int ct = 0; ct < 8; ct++) {
    f32x4 acc = {0.f, 0.f, 0.f, 0.f};
    const ushort* wrow = Wt + (size_t)(ct * 16 + lr) * 128;
#pragma unroll
    for (int kc = 0; kc < 4; kc++) {
      U4B bfr;
      bfr.u = *reinterpret_cast<const uint4*>(wrow + kc * 32 + lg * 8);
      acc = __builtin_amdgcn_mfma_f32_16x16x32_bf16(afr[kc], bfr.v, acc, 0, 0, 0);
    }
    int col = ct * 16 + lr;
    float asw = att_s[col], adw = att_d[col];
    int h = ct >> 1;
#pragma unroll
    for (int v = 0; v < 4; v++) {
      int nrow = row0 + lg * 4 + v;
      if (nrow < M) {
        uint b8 = (uint)__builtin_amdgcn_cvt_pk_fp8_f32(acc[v], acc[v], 0, false);
        hb1[(size_t)nrow * 128 + col] = (uchar)(b8 & 0xFF);
      }
      pS[h][v] += acc[v] * asw;
      pD[h][v] += acc[v] * adw;
    }
  }
  // reduce attention partials across the 16 lanes of each lg-group
#pragma unroll
  for (int off = 1; off < 16; off <<= 1) {
#pragma unroll
    for (int h = 0; h < 4; h++)
#pragma unroll
      for (int v = 0; v < 4; v++) {
        pS[h][v] += __shfl_xor(pS[h][v], off, 16);
        pD[h][v] += __shfl_xor(pD[h][v], off, 16);
      }
  }
  if (lr == 0) {
#pragma unroll
    for (int v = 0; v < 4; v++) {
      int n2 = row0 + lg * 4 + v;
      if (n2 < M) {
#pragma unroll
        for (int h = 0; h < 4; h++) {
          asrc[n2 * 4 + h] = pS[h][v];
          adst[n2 * 4 + h] = pD[h][v];
        }
      }
    }
  }
}

// ---------------- GEMM2 (MFMA bf16) + fused att2: hb2 fp8[M][32], asrc2/adst2[M] ----------------
__global__ void k_gemm2(const ushort* __restrict__ A, const ushort* __restrict__ Wt,
                        const float* __restrict__ att_s, const float* __restrict__ att_d,
                        uchar* __restrict__ hb2, float* __restrict__ asrc,
                        float* __restrict__ adst, int M) {
  int wv = threadIdx.x >> 6, l = threadIdx.x & 63;
  int lg = l >> 4, lr = l & 15;
  int row0 = blockIdx.x * 64 + wv * 16;
  int node = row0 + lr;
  bool valid = node < M;
  bf16x8 afr[4];
#pragma unroll
  for (int kc = 0; kc < 4; kc++) {
    U4B a;
    if (valid) a.u = *reinterpret_cast<const uint4*>(A + (size_t)node * 128 + kc * 32 + lg * 8);
    else a.u = make_uint4(0, 0, 0, 0);
    afr[kc] = a.v;
  }
  float pS[4], pD[4];
#pragma unroll
  for (int v = 0; v < 4; v++) { pS[v] = 0.f; pD[v] = 0.f; }
#pragma unroll
  for (int ct = 0; ct < 2; ct++) {
    f32x4 acc = {0.f, 0.f, 0.f, 0.f};
    const ushort* wrow = Wt + (size_t)(ct * 16 + lr) * 128;
#pragma unroll
    for (int kc = 0; kc < 4; kc++) {
      U4B bfr;
      bfr.u = *reinterpret_cast<const uint4*>(wrow + kc * 32 + lg * 8);
      acc = __builtin_amdgcn_mfma_f32_16x16x32_bf16(afr[kc], bfr.v, acc, 0, 0, 0);
    }
    int col = ct * 16 + lr;
    float asw = att_s[col], adw = att_d[col];
#pragma unroll
    for (int v = 0; v < 4; v++) {
      int nrow = row0 + lg * 4 + v;
      if (nrow < M) {
        uint b8 = (uint)__builtin_amdgcn_cvt_pk_fp8_f32(acc[v], acc[v], 0, false);
        hb2[(size_t)nrow * 32 + col] = (uchar)(b8 & 0xFF);
      }
      pS[v] += acc[v] * asw;
      pD[v] += acc[v] * adw;
    }
  }
#pragma unroll
  for (int off = 1; off < 16; off <<= 1) {
#pragma unroll
    for (int v = 0; v < 4; v++) {
      pS[v] += __shfl_xor(pS[v], off, 16);
      pD[v] += __shfl_xor(pD[v], off, 16);
    }
  }
  if (lr == 0) {
#pragma unroll
    for (int v = 0; v < 4; v++) {
      int n2 = row0 + lg * 4 + v;
      if (n2 < M) { asrc[n2] = pS[v]; adst[n2] = pD[v]; }
    }
  }
}

// ---------------- layer-1 aggregation: wave/dst, 2 slots x 32 lanes x 4 fp8 ch ----------------
__global__ void k_aggr1(const int* __restrict__ offs, const int* __restrict__ ssrc,
                        const uchar* __restrict__ hb, const float* __restrict__ asrc,
                        const float* __restrict__ adst, const float* __restrict__ bias,
                        ushort* __restrict__ outb, int N) {
  int wid = threadIdx.x >> 6, l = threadIdx.x & 63;
  int d = blockIdx.x * 4 + wid;
  if (d >= N) return;
  int slot = l >> 5;       // 0..1
  int c = l & 31;          // channel cluster: ch c*4 .. c*4+3
  int h = c >> 3;          // head
  float ad = adst[d * 4 + h];
  int beg = offs[d], end = offs[d + 1];
  float a0 = 0.f, a1 = 0.f, a2 = 0.f, a3 = 0.f, ds = 0.f;
  int i = beg;
  for (; i + 4 <= end; i += 4) {
    int e0 = i + slot, e1 = i + 2 + slot;
    int s0 = ssrc[e0], s1 = ssrc[e1];
    float as0 = asrc[s0 * 4 + h], as1 = asrc[s1 * 4 + h];
    uint p0 = *reinterpret_cast<const uint*>(hb + (size_t)s0 * 128 + c * 4);
    uint p1 = *reinterpret_cast<const uint*>(hb + (size_t)s1 * 128 + c * 4);
    float x0 = as0 + ad; x0 = x0 > 0.f ? x0 : NEG * x0;
    float x1 = as1 + ad; x1 = x1 > 0.f ? x1 : NEG * x1;
    float w0 = __expf(x0), w1 = __expf(x1);
    f32x2 f00 = __builtin_amdgcn_cvt_pk_f32_fp8(p0, false);
    f32x2 f01 = __builtin_amdgcn_cvt_pk_f32_fp8(p0, true);
    f32x2 f10 = __builtin_amdgcn_cvt_pk_f32_fp8(p1, false);
    f32x2 f11 = __builtin_amdgcn_cvt_pk_f32_fp8(p1, true);
    a0 += w0 * f00.x + w1 * f10.x;
    a1 += w0 * f00.y + w1 * f10.y;
    a2 += w0 * f01.x + w1 * f11.x;
    a3 += w0 * f01.y + w1 * f11.y;
    ds += w0 + w1;
  }
  for (; i < end; i += 2) {
    int e = i + slot;
    int ec = min(e, end - 1);
    int s = ssrc[ec];
    float as = asrc[s * 4 + h];
    uint p = *reinterpret_cast<const uint*>(hb + (size_t)s * 128 + c * 4);
    float xv = as + ad; xv = xv > 0.f ? xv : NEG * xv;
    float w = __expf(xv);
    w = (e < end) ? w : 0.f;
    f32x2 f0 = __builtin_amdgcn_cvt_pk_f32_fp8(p, false);
    f32x2 f1 = __builtin_amdgcn_cvt_pk_f32_fp8(p, true);
    a0 += w * f0.x; a1 += w * f0.y; a2 += w * f1.x; a3 += w * f1.y;
    ds += w;
  }
  // combine the two slots
  ds += __shfl_xor(ds, 32, 64);
  a0 += __shfl_xor(a0, 32, 64);
  a1 += __shfl_xor(a1, 32, 64);
  a2 += __shfl_xor(a2, 32, 64);
  a3 += __shfl_xor(a3, 32, 64);
  if (slot == 0) {
    float inv = 1.f / ds;
    float r0 = a0 * inv + bias[c * 4 + 0];
    float r1 = a1 * inv + bias[c * 4 + 1];
    float r2 = a2 * inv + bias[c * 4 + 2];
    float r3 = a3 * inv + bias[c * 4 + 3];
    r0 = r0 > 0.f ? r0 : expm1f(r0);
    r1 = r1 > 0.f ? r1 : expm1f(r1);
    r2 = r2 > 0.f ? r2 : expm1f(r2);
    r3 = r3 > 0.f ? r3 : expm1f(r3);
    uint o0 = (uint)f2bf(r0) | ((uint)f2bf(r1) << 16);
    uint o1 = (uint)f2bf(r2) | ((uint)f2bf(r3) << 16);
    *reinterpret_cast<uint2*>(outb + (size_t)d * 128 + c * 4) = make_uint2(o0, o1);
  }
}

// ---------------- layer-2 aggregation: wave/dst, 4 slots x 16 lanes x 2 fp8 ch ----------------
__global__ void k_aggr2(const int* __restrict__ offs, const int* __restrict__ ssrc,
                        const uchar* __restrict__ hb, const float* __restrict__ asrc,
                        const float* __restrict__ adst, const float* __restrict__ bias,
                        float* __restrict__ out, int N) {
  int wid = threadIdx.x >> 6, l = threadIdx.x & 63;
  int d = blockIdx.x * 4 + wid;
  if (d >= N) return;
  int slot = l >> 4;       // 0..3
  int c = l & 15;          // channel pair: ch c*2, c*2+1
  float ad = adst[d];
  int beg = offs[d], end = offs[d + 1];
  float a0 = 0.f, a1 = 0.f, ds = 0.f;
  int i = beg;
  for (; i + 8 <= end; i += 8) {
    int e0 = i + slot, e1 = i + 4 + slot;
    int s0 = ssrc[e0], s1 = ssrc[e1];
    float as0 = asrc[s0], as1 = asrc[s1];
    ushort p0 = *reinterpret_cast<const ushort*>(hb + (size_t)s0 * 32 + c * 2);
    ushort p1 = *reinterpret_cast<const ushort*>(hb + (size_t)s1 * 32 + c * 2);
    float x0 = as0 + ad; x0 = x0 > 0.f ? x0 : NEG * x0;
    float x1 = as1 + ad; x1 = x1 > 0.f ? x1 : NEG * x1;
    float w0 = __expf(x0), w1 = __expf(x1);
    f32x2 f0 = __builtin_amdgcn_cvt_pk_f32_fp8((uint)p0, false);
    f32x2 f1 = __builtin_amdgcn_cvt_pk_f32_fp8((uint)p1, false);
    a0 += w0 * f0.x + w1 * f1.x;
    a1 += w0 * f0.y + w1 * f1.y;
    ds += w0 + w1;
  }
  for (; i < end; i += 4) {
    int e = i + slot;
    int ec = min(e, end - 1);
    int s = ssrc[ec];
    float as = asrc[s];
    ushort p = *reinterpret_cast<const ushort*>(hb + (size_t)s * 32 + c * 2);
    float xv = as + ad; xv = xv > 0.f ? xv : NEG * xv;
    float w = __expf(xv);
    w = (e < end) ? w : 0.f;
    f32x2 f = __builtin_amdgcn_cvt_pk_f32_fp8((uint)p, false);
    a0 += w * f.x; a1 += w * f.y; ds += w;
  }
#pragma unroll
  for (int off = 16; off < 64; off <<= 1) {
    ds += __shfl_xor(ds, off, 64);
    a0 += __shfl_xor(a0, off, 64);
    a1 += __shfl_xor(a1, off, 64);
  }
  if (l < 16) {
    float inv = 1.f / ds;
    float r0 = a0 * inv + bias[c * 2];
    float r1 = a1 * inv + bias[c * 2 + 1];
    r0 = r0 > 0.f ? r0 : expm1f(r0);
    r1 = r1 > 0.f ? r1 : expm1f(r1);
    *reinterpret_cast<float2*>(out + (size_t)d * 32 + c * 2) = make_float2(r0, r1);
  }
}

// ---------------- pool (mean per graph, batch sorted) + FC ----------------
__global__ void k_pool_fc(const float* __restrict__ h2, const int* __restrict__ batch,
                          const float* __restrict__ fcW, const float* __restrict__ fcb,
                          float* __restrict__ out, int N) {
  int g = blockIdx.x;
  int lo = 0, hi = N;
  while (lo < hi) { int mid = (lo + hi) >> 1; if (batch[mid] < g) lo = mid + 1; else hi = mid; }
  int beg = lo;
  hi = N;
  while (lo < hi) { int mid = (lo + hi) >> 1; if (batch[mid] < g + 1) lo = mid + 1; else hi = mid; }
  int end = lo;
  int t = threadIdx.x, c = t & 31, sub = t >> 5;
  float acc = 0.f;
  for (int n = beg + sub; n < end; n += 8) acc += h2[(size_t)n * 32 + c];
  __shared__ float red[8][32];
  __shared__ float pooled[32];
  red[sub][c] = acc;
  __syncthreads();
  if (sub == 0) {
    float s = 0.f;
#pragma unroll
    for (int i = 0; i < 8; i++) s += red[i][c];
    float cnt = (float)(end - beg);
    pooled[c] = s / fmaxf(cnt, 1.f);
  }
  __syncthreads();
  if (t < 16) {
    float r = fcb[t];
#pragma unroll
    for (int cc = 0; cc < 32; cc++) r += pooled[cc] * fcW[cc * 16 + t];
    out[g * 16 + t] = r;
  }
}

// ---------------- host launch ----------------
extern "C" void kernel_launch(void* const* d_in, const int* in_sizes, int n_in,
                              void* d_out, int out_size, void* d_ws, size_t ws_size,
                              hipStream_t stream) {
  const float* x     = (const float*)d_in[0];
  const int*   ei    = (const int*)d_in[1];
  const int*   batch = (const int*)d_in[2];
  const float* nw    = (const float*)d_in[3];
  const float* W1    = (const float*)d_in[4];
  const float* as1w  = (const float*)d_in[5];
  const float* ad1w  = (const float*)d_in[6];
  const float* b1    = (const float*)d_in[7];
  const float* W2    = (const float*)d_in[8];
  const float* as2w  = (const float*)d_in[9];
  const float* ad2w  = (const float*)d_in[10];
  const float* b2    = (const float*)d_in[11];
  const float* fcW   = (const float*)d_in[12];
  const float* fcb   = (const float*)d_in[13];
  float* out = (float*)d_out;

  const int N = in_sizes[0] / 128;
  const int E = in_sizes[1] / 2;
  const int Etot = E + N;
  const int NB = (N + 511) >> 9;

  char* w = (char*)d_ws;
  size_t ofs = 0;
  auto alloc = [&](size_t bytes) {
    char* p = w + ofs;
    ofs += (bytes + 255) & ~(size_t)255;
    return p;
  };
  uchar*  hb1    = (uchar*)alloc((size_t)N * 128);        // fp8 layer-1 features
  ushort* out1b  = (ushort*)alloc((size_t)N * 128 * 2);   // bf16 layer-1 output
  uchar*  hb2    = (uchar*)alloc((size_t)N * 32);         // fp8 layer-2 features
  float*  h2     = (float*)alloc((size_t)N * 32 * 4);     // fp32 layer-2 output
  float*  asrc1  = (float*)alloc((size_t)N * 4 * 4);
  float*  adst1  = (float*)alloc((size_t)N * 4 * 4);
  float*  asrc2  = (float*)alloc((size_t)N * 4);
  float*  adst2  = (float*)alloc((size_t)N * 4);
  ushort* Wt1    = (ushort*)alloc(16384 * 2);
  ushort* Wt2    = (ushort*)alloc(4096 * 2);
  int*    bcnt   = (int*)alloc((size_t)(2 * NB) * 4);     // bcnt | bcur
  int*    bcur   = bcnt + NB;
  int*    bstart = (int*)alloc((size_t)(NB + 1) * 4);
  int*    offs   = (int*)alloc((size_t)(N + 1) * 4);
  uint*   bbuf   = (uint*)alloc((size_t)Etot * 4);
  int*    ssrc   = (int*)alloc((size_t)Etot * 4);

  hipMemsetAsync(bcnt, 0, (size_t)(2 * NB) * 4, stream);

  // binned CSR build
  const int nbin = (Etot + 4095) / 4096;
  k_bhist<<<nbin, 256, 0, stream>>>(ei, E, Etot, NB, bcnt);
  k_bscan<<<1, 64, 0, stream>>>(bcnt, NB, bstart, Etot, offs, N);
  k_bin<<<nbin, 256, 0, stream>>>(ei, E, Etot, NB, bstart, bcur, bbuf);
  k_build<<<NB, 512, 0, stream>>>(bbuf, bstart, N, offs, ssrc);

  // weight prep (independent of CSR)
  k_prep<<<80, 256, 0, stream>>>(W1, W2, Wt1, Wt2);

  // layer 1: GEMM+att fused, then aggregation
  k_gemm1<<<(N + 63) / 64, 256, 0, stream>>>(x, Wt1, nw, as1w, ad1w, hb1, asrc1, adst1, N);
  k_aggr1<<<(N + 3) / 4, 256, 0, stream>>>(offs, ssrc, hb1, asrc1, adst1, b1, out1b, N);

  // layer 2
  k_gemm2<<<(N + 63) / 64, 256, 0, stream>>>(out1b, Wt2, as2w, ad2w, hb2, asrc2, adst2, N);
  k_aggr2<<<(N + 3) / 4, 256, 0, stream>>>(offs, ssrc, hb2, asrc2, adst2, b2, h2, N);

  // pool + fc
  k_pool_fc<<<NGRAPH, 256, 0, stream>>>(h2, batch, fcW, fcb, out, N);
}

// Round 7
// 367.684 us; speedup vs baseline: 1.2106x; 1.0501x over previous
//
#include <hip/hip_runtime.h>
#include <cstdint>

#define OUT_C 16
#define NGRAPH 128
#define NEG 0.2f
#define NB_MAX 512      // buckets of 256 dst nodes; N=100K -> 391 buckets
#define BSH 8           // bucket shift
#define BSZ 256         // k_build block size = bucket size

typedef unsigned int uint;
typedef unsigned short ushort;
typedef unsigned char uchar;
typedef __attribute__((ext_vector_type(8))) short bf16x8;
typedef __attribute__((ext_vector_type(4))) float f32x4;
typedef __attribute__((ext_vector_type(2))) float f32x2;

union U4B { uint4 u; bf16x8 v; };

__device__ __forceinline__ ushort f2bf(float f) {
  uint u = __float_as_uint(f);
  uint r = (u + 0x7FFF + ((u >> 16) & 1)) >> 16;   // RNE
  return (ushort)r;
}

__device__ __forceinline__ int wave_incl_scan_i(int v) {
  int lane = threadIdx.x & 63;
#pragma unroll
  for (int off = 1; off < 64; off <<= 1) {
    int u = __shfl_up(v, off, 64);
    if (lane >= off) v += u;
  }
  return v;
}

// ---------------- binned CSR build (bucket = dst >> 8, 256 nodes) ----------------
__global__ void k_bhist(const int* __restrict__ ei, int E, int Etot, int NB,
                        int* __restrict__ bcnt) {
  __shared__ int h[NB_MAX];
  int t = threadIdx.x;
  for (int b = t; b < NB; b += 256) h[b] = 0;
  __syncthreads();
  int base = blockIdx.x * 4096;
  int end = min(base + 4096, Etot);
  for (int e = base + t; e < end; e += 256) {
    int d = (e < E) ? ei[E + e] : (e - E);
    atomicAdd(&h[d >> BSH], 1);
  }
  __syncthreads();
  for (int b = t; b < NB; b += 256) if (h[b]) atomicAdd(&bcnt[b], h[b]);
}

__global__ void k_bscan(const int* __restrict__ bcnt, int NB,
                        int* __restrict__ bstart, int Etot,
                        int* __restrict__ offs, int N) {
  if (threadIdx.x == 0) {
    int run = 0;
    for (int b = 0; b < NB; b++) { bstart[b] = run; run += bcnt[b]; }
    bstart[NB] = run;
    offs[N] = Etot;
  }
}

__global__ void k_bin(const int* __restrict__ ei, int E, int Etot, int NB,
                      const int* __restrict__ bstart, int* __restrict__ bcur,
                      uint* __restrict__ bbuf) {
  __shared__ int h[NB_MAX];
  __shared__ int baseo[NB_MAX];
  int t = threadIdx.x;
  for (int b = t; b < NB; b += 256) h[b] = 0;
  __syncthreads();
  int cbase = blockIdx.x * 4096;
  int cend = min(cbase + 4096, Etot);
  for (int e = cbase + t; e < cend; e += 256) {
    int d = (e < E) ? ei[E + e] : (e - E);
    atomicAdd(&h[d >> BSH], 1);
  }
  __syncthreads();
  for (int b = t; b < NB; b += 256) {
    int c = h[b];
    baseo[b] = c ? atomicAdd(&bcur[b], c) : 0;
    h[b] = 0;
  }
  __syncthreads();
  for (int e = cbase + t; e < cend; e += 256) {
    int s, d;
    if (e < E) { s = ei[e]; d = ei[E + e]; } else { s = e - E; d = s; }
    int b = d >> BSH;
    int r = atomicAdd(&h[b], 1);
    bbuf[bstart[b] + baseo[b] + r] = ((uint)(d & (BSZ - 1)) << 17) | (uint)s;
  }
}

// one block (256 thr) per 256-node bucket: degrees -> scan -> offs; rank+scatter in LDS
__global__ void k_build(const uint* __restrict__ bbuf, const int* __restrict__ bstart,
                        int N, int* __restrict__ offs, int* __restrict__ ssrc) {
  __shared__ int deg[BSZ];
  __shared__ int wsum[4];
  int b = blockIdx.x;
  int t = threadIdx.x;
  int lane = t & 63, wid = t >> 6;
  deg[t] = 0;
  __syncthreads();
  int ebeg = bstart[b], eend = bstart[b + 1];
  for (int i = ebeg + t; i < eend; i += BSZ)
    atomicAdd(&deg[bbuf[i] >> 17], 1);
  __syncthreads();
  int v = deg[t];
  int sv = wave_incl_scan_i(v);
  if (lane == 63) wsum[wid] = sv;
  __syncthreads();
  if (t == 0) {
    int r = 0;
#pragma unroll
    for (int k = 0; k < 4; k++) { int x = wsum[k]; wsum[k] = r; r += x; }
  }
  __syncthreads();
  int excl = wsum[wid] + sv - v;
  int node = (b << BSH) + t;
  if (node < N) offs[node] = ebeg + excl;
  __syncthreads();
  deg[t] = excl;                     // becomes local cursor
  __syncthreads();
  for (int i = ebeg + t; i < eend; i += BSZ) {
    uint rec = bbuf[i];
    int r = atomicAdd(&deg[rec >> 17], 1);
    ssrc[ebeg + r] = (int)(rec & 0x1FFFF);
  }
}

// ---------------- weight prep: Wt1[n][k]=bf16(W1[k][n]), Wt2[n][k]=bf16(W2[k][n]) ----------------
__global__ void k_prep(const float* __restrict__ W1, const float* __restrict__ W2,
                       ushort* __restrict__ Wt1, ushort* __restrict__ Wt2) {
  int t = blockIdx.x * 256 + threadIdx.x;
  if (t < 16384) {
    int n = t >> 7, k = t & 127;
    Wt1[t] = f2bf(W1[k * 128 + n]);
  } else if (t < 16384 + 4096) {
    int u = t - 16384;
    int n = u >> 7, k = u & 127;
    Wt2[u] = f2bf(W2[k * 32 + n]);
  }
}

// ---------------- GEMM1 (MFMA bf16) + fused att1: hb1 fp8[M][128], asrc/adst[M][4] ----------------
__global__ void k_gemm1(const float* __restrict__ x, const ushort* __restrict__ Wt,
                        const float* __restrict__ nw, const float* __restrict__ att_s,
                        const float* __restrict__ att_d, uchar* __restrict__ hb1,
                        float* __restrict__ asrc, float* __restrict__ adst, int M) {
  int wv = threadIdx.x >> 6, l = threadIdx.x & 63;
  int lg = l >> 4, lr = l & 15;
  int row0 = blockIdx.x * 64 + wv * 16;
  int node = row0 + lr;
  bool valid = node < M;
  float sc = valid ? nw[node] : 0.f;
  bf16x8 afr[4];
  const float* xr = x + (size_t)node * 128;
#pragma unroll
  for (int kc = 0; kc < 4; kc++) {
    float v[8];
    if (valid) {
      float4 q0 = *reinterpret_cast<const float4*>(xr + kc * 32 + lg * 8);
      float4 q1 = *reinterpret_cast<const float4*>(xr + kc * 32 + lg * 8 + 4);
      v[0] = q0.x; v[1] = q0.y; v[2] = q0.z; v[3] = q0.w;
      v[4] = q1.x; v[5] = q1.y; v[6] = q1.z; v[7] = q1.w;
    } else {
#pragma unroll
      for (int j = 0; j < 8; j++) v[j] = 0.f;
    }
    U4B a;
    uint pk0 = (uint)f2bf(v[0] * sc) | ((uint)f2bf(v[1] * sc) << 16);
    uint pk1 = (uint)f2bf(v[2] * sc) | ((uint)f2bf(v[3] * sc) << 16);
    uint pk2 = (uint)f2bf(v[4] * sc) | ((uint)f2bf(v[5] * sc) << 16);
    uint pk3 = (uint)f2bf(v[6] * sc) | ((uint)f2bf(v[7] * sc) << 16);
    a.u = make_uint4(pk0, pk1, pk2, pk3);
    afr[kc] = a.v;
  }
  float pS[4][4], pD[4][4];
#pragma unroll
  for (int h = 0; h < 4; h++)
#pragma unroll
    for (int v = 0; v < 4; v++) { pS[h][v] = 0.f; pD[h][v] = 0.f; }
#pragma unroll
  for (int ct = 0; ct < 8; ct++) {
    f32x4 acc = {0.f, 0.f, 0.f, 0.f};
    const ushort* wrow = Wt + (size_t)(ct * 16 + lr) * 128;
#pragma unroll
    for (int kc = 0; kc < 4; kc++) {
      U4B bfr;
      bfr.u = *reinterpret_cast<const uint4*>(wrow + kc * 32 + lg * 8);
      acc = __builtin_amdgcn_mfma_f32_16x16x32_bf16(afr[kc], bfr.v, acc, 0, 0, 0);
    }
    int col = ct * 16 + lr;
    float asw = att_s[col], adw = att_d[col];
    int h = ct >> 1;
#pragma unroll
    for (int v = 0; v < 4; v++) {
      int nrow = row0 + lg * 4 + v;
      if (nrow < M) {
        uint b8 = (uint)__builtin_amdgcn_cvt_pk_fp8_f32(acc[v], acc[v], 0, false);
        hb1[(size_t)nrow * 128 + col] = (uchar)(b8 & 0xFF);
      }
      pS[h][v] += acc[v] * asw;
      pD[h][v] += acc[v] * adw;
    }
  }
#pragma unroll
  for (int off = 1; off < 16; off <<= 1) {
#pragma unroll
    for (int h = 0; h < 4; h++)
#pragma unroll
      for (int v = 0; v < 4; v++) {
        pS[h][v] += __shfl_xor(pS[h][v], off, 16);
        pD[h][v] += __shfl_xor(pD[h][v], off, 16);
      }
  }
  if (lr == 0) {
#pragma unroll
    for (int v = 0; v < 4; v++) {
      int n2 = row0 + lg * 4 + v;
      if (n2 < M) {
#pragma unroll
        for (int h = 0; h < 4; h++) {
          asrc[n2 * 4 + h] = pS[h][v];
          adst[n2 * 4 + h] = pD[h][v];
        }
      }
    }
  }
}

// ---------------- GEMM2 (MFMA bf16) + fused att2: hb2 fp8[M][32], asrc2/adst2[M] ----------------
__global__ void k_gemm2(const ushort* __restrict__ A, const ushort* __restrict__ Wt,
                        const float* __restrict__ att_s, const float* __restrict__ att_d,
                        uchar* __restrict__ hb2, float* __restrict__ asrc,
                        float* __restrict__ adst, int M) {
  int wv = threadIdx.x >> 6, l = threadIdx.x & 63;
  int lg = l >> 4, lr = l & 15;
  int row0 = blockIdx.x * 64 + wv * 16;
  int node = row0 + lr;
  bool valid = node < M;
  bf16x8 afr[4];
#pragma unroll
  for (int kc = 0; kc < 4; kc++) {
    U4B a;
    if (valid) a.u = *reinterpret_cast<const uint4*>(A + (size_t)node * 128 + kc * 32 + lg * 8);
    else a.u = make_uint4(0, 0, 0, 0);
    afr[kc] = a.v;
  }
  float pS[4], pD[4];
#pragma unroll
  for (int v = 0; v < 4; v++) { pS[v] = 0.f; pD[v] = 0.f; }
#pragma unroll
  for (int ct = 0; ct < 2; ct++) {
    f32x4 acc = {0.f, 0.f, 0.f, 0.f};
    const ushort* wrow = Wt + (size_t)(ct * 16 + lr) * 128;
#pragma unroll
    for (int kc = 0; kc < 4; kc++) {
      U4B bfr;
      bfr.u = *reinterpret_cast<const uint4*>(wrow + kc * 32 + lg * 8);
      acc = __builtin_amdgcn_mfma_f32_16x16x32_bf16(afr[kc], bfr.v, acc, 0, 0, 0);
    }
    int col = ct * 16 + lr;
    float asw = att_s[col], adw = att_d[col];
#pragma unroll
    for (int v = 0; v < 4; v++) {
      int nrow = row0 + lg * 4 + v;
      if (nrow < M) {
        uint b8 = (uint)__builtin_amdgcn_cvt_pk_fp8_f32(acc[v], acc[v], 0, false);
        hb2[(size_t)nrow * 32 + col] = (uchar)(b8 & 0xFF);
      }
      pS[v] += acc[v] * asw;
      pD[v] += acc[v] * adw;
    }
  }
#pragma unroll
  for (int off = 1; off < 16; off <<= 1) {
#pragma unroll
    for (int v = 0; v < 4; v++) {
      pS[v] += __shfl_xor(pS[v], off, 16);
      pD[v] += __shfl_xor(pD[v], off, 16);
    }
  }
  if (lr == 0) {
#pragma unroll
    for (int v = 0; v < 4; v++) {
      int n2 = row0 + lg * 4 + v;
      if (n2 < M) { asrc[n2] = pS[v]; adst[n2] = pD[v]; }
    }
  }
}

// ---- layer-1 aggregation: wave/dst, 8 slots x 8 lanes x uint4 (full 128B row per edge) ----
// Epilogue: reduce-scatter butterfly; each lane ends owning 2 channels.
__global__ void k_aggr1(const int* __restrict__ offs, const int* __restrict__ ssrc,
                        const uchar* __restrict__ hb, const float* __restrict__ asrc,
                        const float* __restrict__ adst, const float* __restrict__ bias,
                        ushort* __restrict__ outb, int N) {
  int wid = threadIdx.x >> 6, l = threadIdx.x & 63;
  int d = blockIdx.x * 4 + wid;
  if (d >= N) return;
  int slot = l >> 3;       // 0..7 edge slot
  int k = l & 7;           // channel block: ch k*16 .. +15
  int h = k >> 1;          // head of this lane's channels
  float ad = adst[d * 4 + h];
  int beg = offs[d], end = offs[d + 1];
  float a[16] = {};
  float ds = 0.f;
  for (int i = beg; i < end; i += 8) {
    int e = i + slot;
    int ec = min(e, end - 1);
    int s = ssrc[ec];
    float xv = asrc[s * 4 + h] + ad;
    xv = xv > 0.f ? xv : NEG * xv;
    float w = __expf(xv);
    w = (e < end) ? w : 0.f;
    uint4 p = *reinterpret_cast<const uint4*>(hb + (size_t)s * 128 + k * 16);
    uint pu[4] = {p.x, p.y, p.z, p.w};
#pragma unroll
    for (int q = 0; q < 4; q++) {
      f32x2 f0 = __builtin_amdgcn_cvt_pk_f32_fp8(pu[q], false);
      f32x2 f1 = __builtin_amdgcn_cvt_pk_f32_fp8(pu[q], true);
      a[q * 4 + 0] += w * f0.x;
      a[q * 4 + 1] += w * f0.y;
      a[q * 4 + 2] += w * f1.x;
      a[q * 4 + 3] += w * f1.y;
    }
    ds += w;
  }
  int b3 = (l >> 3) & 1, b4 = (l >> 4) & 1, b5 = (l >> 5) & 1;
  // stage 1 (xor 8): keep 8 channels
  float t8[8];
#pragma unroll
  for (int r = 0; r < 8; r++) {
    float send = b3 ? a[r] : a[r + 8];
    float recv = __shfl_xor(send, 8, 64);
    t8[r] = (b3 ? a[r + 8] : a[r]) + recv;
  }
  // stage 2 (xor 16): keep 4
  float t4[4];
#pragma unroll
  for (int r = 0; r < 4; r++) {
    float send = b4 ? t8[r] : t8[r + 4];
    float recv = __shfl_xor(send, 16, 64);
    t4[r] = (b4 ? t8[r + 4] : t8[r]) + recv;
  }
  // stage 3 (xor 32): keep 2
  float t2[2];
#pragma unroll
  for (int r = 0; r < 2; r++) {
    float send = b5 ? t4[r] : t4[r + 2];
    float recv = __shfl_xor(send, 32, 64);
    t2[r] = (b5 ? t4[r + 2] : t4[r]) + recv;
  }
  // ds: full butterfly over the 8 slots
  ds += __shfl_xor(ds, 8, 64);
  ds += __shfl_xor(ds, 16, 64);
  ds += __shfl_xor(ds, 32, 64);
  float inv = 1.f / ds;
  int c0 = k * 16 + b3 * 8 + b4 * 4 + b5 * 2;
  float r0 = t2[0] * inv + bias[c0];
  float r1 = t2[1] * inv + bias[c0 + 1];
  r0 = r0 > 0.f ? r0 : expm1f(r0);
  r1 = r1 > 0.f ? r1 : expm1f(r1);
  *reinterpret_cast<uint*>(outb + (size_t)d * 128 + c0) =
      (uint)f2bf(r0) | ((uint)f2bf(r1) << 16);
}

// ---- layer-2 aggregation: wave/dst, 16 slots x 4 lanes x uint2 (full 32B row per edge) ----
__global__ void k_aggr2(const int* __restrict__ offs, const int* __restrict__ ssrc,
                        const uchar* __restrict__ hb, const float* __restrict__ asrc,
                        const float* __restrict__ adst, const float* __restrict__ bias,
                        float* __restrict__ out, int N) {
  int wid = threadIdx.x >> 6, l = threadIdx.x & 63;
  int d = blockIdx.x * 4 + wid;
  if (d >= N) return;
  int slot = l >> 2;       // 0..15 edge slot
  int k = l & 3;           // channel block: ch k*8 .. +7
  float ad = adst[d];
  int beg = offs[d], end = offs[d + 1];
  float a[8] = {};
  float ds = 0.f;
  for (int i = beg; i < end; i += 16) {
    int e = i + slot;
    int ec = min(e, end - 1);
    int s = ssrc[ec];
    float xv = asrc[s] + ad;
    xv = xv > 0.f ? xv : NEG * xv;
    float w = __expf(xv);
    w = (e < end) ? w : 0.f;
    uint2 p = *reinterpret_cast<const uint2*>(hb + (size_t)s * 32 + k * 8);
    f32x2 f0 = __builtin_amdgcn_cvt_pk_f32_fp8(p.x, false);
    f32x2 f1 = __builtin_amdgcn_cvt_pk_f32_fp8(p.x, true);
    f32x2 f2 = __builtin_amdgcn_cvt_pk_f32_fp8(p.y, false);
    f32x2 f3 = __builtin_amdgcn_cvt_pk_f32_fp8(p.y, true);
    a[0] += w * f0.x; a[1] += w * f0.y; a[2] += w * f1.x; a[3] += w * f1.y;
    a[4] += w * f2.x; a[5] += w * f2.y; a[6] += w * f3.x; a[7] += w * f3.y;
    ds += w;
  }
  int b2 = (l >> 2) & 1, b3 = (l >> 3) & 1, b4 = (l >> 4) & 1;
  // stage 1 (xor 4): keep 4
  float t4[4];
#pragma unroll
  for (int r = 0; r < 4; r++) {
    float send = b2 ? a[r] : a[r + 4];
    float recv = __shfl_xor(send, 4, 64);
    t4[r] = (b2 ? a[r + 4] : a[r]) + recv;
  }
  // stage 2 (xor 8): keep 2
  float t2[2];
#pragma unroll
  for (int r = 0; r < 2; r++) {
    float send = b3 ? t4[r] : t4[r + 2];
    float recv = __shfl_xor(send, 8, 64);
    t2[r] = (b3 ? t4[r + 2] : t4[r]) + recv;
  }
  // stage 3 (xor 16): keep 1
  float send = b4 ? t2[0] : t2[1];
  float recv = __shfl_xor(send, 16, 64);
  float t1 = (b4 ? t2[1] : t2[0]) + recv;
  // stage 4 (xor 32): full add (slot bit5)
  t1 += __shfl_xor(t1, 32, 64);
  // ds: full butterfly over the 16 slots
  ds += __shfl_xor(ds, 4, 64);
  ds += __shfl_xor(ds, 8, 64);
  ds += __shfl_xor(ds, 16, 64);
  ds += __shfl_xor(ds, 32, 64);
  if (l < 32) {
    int c = k * 8 + b2 * 4 + b3 * 2 + b4;
    float r = t1 / ds + bias[c];
    r = r > 0.f ? r : expm1f(r);
    out[(size_t)d * 32 + c] = r;
  }
}

// ---------------- pool (mean per graph, batch sorted) + FC ----------------
__global__ void k_pool_fc(const float* __restrict__ h2, const int* __restrict__ batch,
                          const float* __restrict__ fcW, const float* __restrict__ fcb,
                          float* __restrict__ out, int N) {
  int g = blockIdx.x;
  int lo = 0, hi = N;
  while (lo < hi) { int mid = (lo + hi) >> 1; if (batch[mid] < g) lo = mid + 1; else hi = mid; }
  int beg = lo;
  hi = N;
  while (lo < hi) { int mid = (lo + hi) >> 1; if (batch[mid] < g + 1) lo = mid + 1; else hi = mid; }
  int end = lo;
  int t = threadIdx.x, c = t & 31, sub = t >> 5;
  float acc = 0.f;
  for (int n = beg + sub; n < end; n += 8) acc += h2[(size_t)n * 32 + c];
  __shared__ float red[8][32];
  __shared__ float pooled[32];
  red[sub][c] = acc;
  __syncthreads();
  if (sub == 0) {
    float s = 0.f;
#pragma unroll
    for (int i = 0; i < 8; i++) s += red[i][c];
    float cnt = (float)(end - beg);
    pooled[c] = s / fmaxf(cnt, 1.f);
  }
  __syncthreads();
  if (t < 16) {
    float r = fcb[t];
#pragma unroll
    for (int cc = 0; cc < 32; cc++) r += pooled[cc] * fcW[cc * 16 + t];
    out[g * 16 + t] = r;
  }
}

// ---------------- host launch ----------------
extern "C" void kernel_launch(void* const* d_in, const int* in_sizes, int n_in,
                              void* d_out, int out_size, void* d_ws, size_t ws_size,
                              hipStream_t stream) {
  const float* x     = (const float*)d_in[0];
  const int*   ei    = (const int*)d_in[1];
  const int*   batch = (const int*)d_in[2];
  const float* nw    = (const float*)d_in[3];
  const float* W1    = (const float*)d_in[4];
  const float* as1w  = (const float*)d_in[5];
  const float* ad1w  = (const float*)d_in[6];
  const float* b1    = (const float*)d_in[7];
  const float* W2    = (const float*)d_in[8];
  const float* as2w  = (const float*)d_in[9];
  const float* ad2w  = (const float*)d_in[10];
  const float* b2    = (const float*)d_in[11];
  const float* fcW   = (const float*)d_in[12];
  const float* fcb   = (const float*)d_in[13];
  float* out = (float*)d_out;

  const int N = in_sizes[0] / 128;
  const int E = in_sizes[1] / 2;
  const int Etot = E + N;
  const int NB = (N + BSZ - 1) >> BSH;

  char* w = (char*)d_ws;
  size_t ofs = 0;
  auto alloc = [&](size_t bytes) {
    char* p = w + ofs;
    ofs += (bytes + 255) & ~(size_t)255;
    return p;
  };
  uchar*  hb1    = (uchar*)alloc((size_t)N * 128);        // fp8 layer-1 features
  ushort* out1b  = (ushort*)alloc((size_t)N * 128 * 2);   // bf16 layer-1 output
  uchar*  hb2    = (uchar*)alloc((size_t)N * 32);         // fp8 layer-2 features
  float*  h2     = (float*)alloc((size_t)N * 32 * 4);     // fp32 layer-2 output
  float*  asrc1  = (float*)alloc((size_t)N * 4 * 4);
  float*  adst1  = (float*)alloc((size_t)N * 4 * 4);
  float*  asrc2  = (float*)alloc((size_t)N * 4);
  float*  adst2  = (float*)alloc((size_t)N * 4);
  ushort* Wt1    = (ushort*)alloc(16384 * 2);
  ushort* Wt2    = (ushort*)alloc(4096 * 2);
  int*    bcnt   = (int*)alloc((size_t)(2 * NB) * 4);     // bcnt | bcur
  int*    bcur   = bcnt + NB;
  int*    bstart = (int*)alloc((size_t)(NB + 1) * 4);
  int*    offs   = (int*)alloc((size_t)(N + 1) * 4);
  uint*   bbuf   = (uint*)alloc((size_t)Etot * 4);
  int*    ssrc   = (int*)alloc((size_t)Etot * 4);

  hipMemsetAsync(bcnt, 0, (size_t)(2 * NB) * 4, stream);

  // binned CSR build
  const int nbin = (Etot + 4095) / 4096;
  k_bhist<<<nbin, 256, 0, stream>>>(ei, E, Etot, NB, bcnt);
  k_bscan<<<1, 64, 0, stream>>>(bcnt, NB, bstart, Etot, offs, N);
  k_bin<<<nbin, 256, 0, stream>>>(ei, E, Etot, NB, bstart, bcur, bbuf);
  k_build<<<NB, BSZ, 0, stream>>>(bbuf, bstart, N, offs, ssrc);

  // weight prep (independent of CSR)
  k_prep<<<80, 256, 0, stream>>>(W1, W2, Wt1, Wt2);

  // layer 1: GEMM+att fused, then aggregation
  k_gemm1<<<(N + 63) / 64, 256, 0, stream>>>(x, Wt1, nw, as1w, ad1w, hb1, asrc1, adst1, N);
  k_aggr1<<<(N + 3) / 4, 256, 0, stream>>>(offs, ssrc, hb1, asrc1, adst1, b1, out1b, N);

  // layer 2
  k_gemm2<<<(N + 63) / 64, 256, 0, stream>>>(out1b, Wt2, as2w, ad2w, hb2, asrc2, adst2, N);
  k_aggr2<<<(N + 3) / 4, 256, 0, stream>>>(offs, ssrc, hb2, asrc2, adst2, b2, h2, N);

  // pool + fc
  k_pool_fc<<<NGRAPH, 256, 0, stream>>>(h2, batch, fcW, fcb, out, N);
}

// Round 8
// 325.861 us; speedup vs baseline: 1.3660x; 1.1283x over previous
//
#include <hip/hip_runtime.h>
#include <cstdint>

#define OUT_C 16
#define NGRAPH 128
#define NEG 0.2f
#define NB_MAX 512      // buckets of 256 dst nodes; N=100K -> 391 buckets
#define BSH 8           // bucket shift
#define BSZ 256         // k_build block size = bucket size
#define CAP 8192        // bbuf slots per bucket (expected max ~4600)

typedef unsigned int uint;
typedef unsigned short ushort;
typedef unsigned char uchar;
typedef __attribute__((ext_vector_type(8))) short bf16x8;
typedef __attribute__((ext_vector_type(4))) float f32x4;
typedef __attribute__((ext_vector_type(2))) float f32x2;

union U4B { uint4 u; bf16x8 v; };

__device__ __forceinline__ ushort f2bf(float f) {
  uint u = __float_as_uint(f);
  uint r = (u + 0x7FFF + ((u >> 16) & 1)) >> 16;   // RNE
  return (ushort)r;
}

__device__ __forceinline__ int wave_incl_scan_i(int v) {
  int lane = threadIdx.x & 63;
#pragma unroll
  for (int off = 1; off < 64; off <<= 1) {
    int u = __shfl_up(v, off, 64);
    if (lane >= off) v += u;
  }
  return v;
}

// ---------------- k_bin: per-block LDS hist -> bucket alloc -> scatter; + weight prep ----------------
// blocks [0,nbin): bin 4096 edges each into bbuf[bucket][CAP].
// blocks [nbin,nbin+80): transpose W1/W2 to bf16 Wt1/Wt2.
__global__ void k_bin(const int* __restrict__ ei,
                      const float* __restrict__ W1, const float* __restrict__ W2,
                      ushort* __restrict__ Wt1, ushort* __restrict__ Wt2,
                      int E, int Etot, int NB, int nbin,
                      int* __restrict__ bcur, uint* __restrict__ bbuf) {
  if (blockIdx.x >= nbin) {
    int t2 = (blockIdx.x - nbin) * 256 + threadIdx.x;
    if (t2 < 16384) {
      int n = t2 >> 7, k = t2 & 127;
      Wt1[t2] = f2bf(W1[k * 128 + n]);
    } else {
      int u = t2 - 16384;
      int n = u >> 7, k = u & 127;
      Wt2[u] = f2bf(W2[k * 32 + n]);
    }
    return;
  }
  __shared__ int h[NB_MAX];
  __shared__ int baseo[NB_MAX];
  int t = threadIdx.x;
  for (int b = t; b < NB; b += 256) h[b] = 0;
  __syncthreads();
  int cbase = blockIdx.x * 4096;
  int cend = min(cbase + 4096, Etot);
  for (int e = cbase + t; e < cend; e += 256) {
    int d = (e < E) ? ei[E + e] : (e - E);
    atomicAdd(&h[d >> BSH], 1);
  }
  __syncthreads();
  for (int b = t; b < NB; b += 256) {
    int c = h[b];
    baseo[b] = c ? atomicAdd(&bcur[b], c) : 0;
    h[b] = 0;
  }
  __syncthreads();
  for (int e = cbase + t; e < cend; e += 256) {
    int s, d;
    if (e < E) { s = ei[e]; d = ei[E + e]; } else { s = e - E; d = s; }
    int b = d >> BSH;
    int r = atomicAdd(&h[b], 1);
    bbuf[(size_t)b * CAP + baseo[b] + r] = ((uint)(d & (BSZ - 1)) << 17) | (uint)s;
  }
}

// ---------------- k_build: one block per bucket ----------------
// Redundant 256-thread scan of bcur -> bucket starts (sst); then degree hist,
// local scan -> offs; rank+scatter -> ssrc (globally dst-contiguous CSR).
__global__ void k_build(const uint* __restrict__ bbuf, const int* __restrict__ bcur,
                        int NB, int N, int* __restrict__ offs, int* __restrict__ ssrc) {
  __shared__ int sst[NB_MAX + 1];
  __shared__ int wsum2[4];
  __shared__ int deg[BSZ];
  int t = threadIdx.x, lane = t & 63, wid = t >> 6;
  // --- parallel exclusive scan of bcur[0..NB) over 512 virtual slots ---
  int v0 = (2 * t < NB) ? bcur[2 * t] : 0;
  int v1 = (2 * t + 1 < NB) ? bcur[2 * t + 1] : 0;
  int s = v0 + v1;
  int sv = wave_incl_scan_i(s);
  if (lane == 63) wsum2[wid] = sv;
  deg[t] = 0;
  __syncthreads();
  if (t == 0) {
    int r = 0;
#pragma unroll
    for (int k = 0; k < 4; k++) { int x = wsum2[k]; wsum2[k] = r; r += x; }
  }
  __syncthreads();
  int excl = wsum2[wid] + sv - s;
  sst[2 * t] = excl;
  sst[2 * t + 1] = excl + v0;
  if (t == 255) sst[512] = excl + v0 + v1;
  __syncthreads();
  int b = blockIdx.x;
  int ebeg = sst[b], eend = sst[b + 1];
  int cnt = eend - ebeg;
  // --- degree histogram ---
  for (int i = t; i < cnt; i += BSZ)
    atomicAdd(&deg[bbuf[(size_t)b * CAP + i] >> 17], 1);
  __syncthreads();
  int v = deg[t];
  int sv2 = wave_incl_scan_i(v);
  if (lane == 63) wsum2[wid] = sv2;
  __syncthreads();
  if (t == 0) {
    int r = 0;
#pragma unroll
    for (int k = 0; k < 4; k++) { int x = wsum2[k]; wsum2[k] = r; r += x; }
  }
  __syncthreads();
  int excl2 = wsum2[wid] + sv2 - v;
  int node = (b << BSH) + t;
  if (node < N) offs[node] = ebeg + excl2;
  if (b == 0 && t == 0) offs[N] = sst[512];
  __syncthreads();
  deg[t] = excl2;                    // becomes local cursor
  __syncthreads();
  for (int i = t; i < cnt; i += BSZ) {
    uint rec = bbuf[(size_t)b * CAP + i];
    int r = atomicAdd(&deg[rec >> 17], 1);
    ssrc[ebeg + r] = (int)(rec & 0x1FFFF);
  }
}

// ---------------- GEMM1 (MFMA bf16) + fused att1: hb1 fp8[M][128], asrc/adst[M][4] ----------------
__global__ void k_gemm1(const float* __restrict__ x, const ushort* __restrict__ Wt,
                        const float* __restrict__ nw, const float* __restrict__ att_s,
                        const float* __restrict__ att_d, uchar* __restrict__ hb1,
                        float* __restrict__ asrc, float* __restrict__ adst, int M) {
  int wv = threadIdx.x >> 6, l = threadIdx.x & 63;
  int lg = l >> 4, lr = l & 15;
  int row0 = blockIdx.x * 64 + wv * 16;
  int node = row0 + lr;
  bool valid = node < M;
  float sc = valid ? nw[node] : 0.f;
  bf16x8 afr[4];
  const float* xr = x + (size_t)node * 128;
#pragma unroll
  for (int kc = 0; kc < 4; kc++) {
    float v[8];
    if (valid) {
      float4 q0 = *reinterpret_cast<const float4*>(xr + kc * 32 + lg * 8);
      float4 q1 = *reinterpret_cast<const float4*>(xr + kc * 32 + lg * 8 + 4);
      v[0] = q0.x; v[1] = q0.y; v[2] = q0.z; v[3] = q0.w;
      v[4] = q1.x; v[5] = q1.y; v[6] = q1.z; v[7] = q1.w;
    } else {
#pragma unroll
      for (int j = 0; j < 8; j++) v[j] = 0.f;
    }
    U4B a;
    uint pk0 = (uint)f2bf(v[0] * sc) | ((uint)f2bf(v[1] * sc) << 16);
    uint pk1 = (uint)f2bf(v[2] * sc) | ((uint)f2bf(v[3] * sc) << 16);
    uint pk2 = (uint)f2bf(v[4] * sc) | ((uint)f2bf(v[5] * sc) << 16);
    uint pk3 = (uint)f2bf(v[6] * sc) | ((uint)f2bf(v[7] * sc) << 16);
    a.u = make_uint4(pk0, pk1, pk2, pk3);
    afr[kc] = a.v;
  }
  float pS[4][4], pD[4][4];
#pragma unroll
  for (int h = 0; h < 4; h++)
#pragma unroll
    for (int v = 0; v < 4; v++) { pS[h][v] = 0.f; pD[h][v] = 0.f; }
#pragma unroll
  for (int ct = 0; ct < 8; ct++) {
    f32x4 acc = {0.f, 0.f, 0.f, 0.f};
    const ushort* wrow = Wt + (size_t)(ct * 16 + lr) * 128;
#pragma unroll
    for (int kc = 0; kc < 4; kc++) {
      U4B bfr;
      bfr.u = *reinterpret_cast<const uint4*>(wrow + kc * 32 + lg * 8);
      acc = __builtin_amdgcn_mfma_f32_16x16x32_bf16(afr[kc], bfr.v, acc, 0, 0, 0);
    }
    int col = ct * 16 + lr;
    float asw = att_s[col], adw = att_d[col];
    int h = ct >> 1;
#pragma unroll
    for (int v = 0; v < 4; v++) {
      int nrow = row0 + lg * 4 + v;
      if (nrow < M) {
        uint b8 = (uint)__builtin_amdgcn_cvt_pk_fp8_f32(acc[v], acc[v], 0, false);
        hb1[(size_t)nrow * 128 + col] = (uchar)(b8 & 0xFF);
      }
      pS[h][v] += acc[v] * asw;
      pD[h][v] += acc[v] * adw;
    }
  }
#pragma unroll
  for (int off = 1; off < 16; off <<= 1) {
#pragma unroll
    for (int h = 0; h < 4; h++)
#pragma unroll
      for (int v = 0; v < 4; v++) {
        pS[h][v] += __shfl_xor(pS[h][v], off, 16);
        pD[h][v] += __shfl_xor(pD[h][v], off, 16);
      }
  }
  if (lr == 0) {
#pragma unroll
    for (int v = 0; v < 4; v++) {
      int n2 = row0 + lg * 4 + v;
      if (n2 < M) {
#pragma unroll
        for (int h = 0; h < 4; h++) {
          asrc[n2 * 4 + h] = pS[h][v];
          adst[n2 * 4 + h] = pD[h][v];
        }
      }
    }
  }
}

// ---------------- GEMM2 (MFMA bf16) + fused att2: hb2 fp8[M][32], asrc2/adst2[M] ----------------
__global__ void k_gemm2(const ushort* __restrict__ A, const ushort* __restrict__ Wt,
                        const float* __restrict__ att_s, const float* __restrict__ att_d,
                        uchar* __restrict__ hb2, float* __restrict__ asrc,
                        float* __restrict__ adst, int M) {
  int wv = threadIdx.x >> 6, l = threadIdx.x & 63;
  int lg = l >> 4, lr = l & 15;
  int row0 = blockIdx.x * 64 + wv * 16;
  int node = row0 + lr;
  bool valid = node < M;
  bf16x8 afr[4];
#pragma unroll
  for (int kc = 0; kc < 4; kc++) {
    U4B a;
    if (valid) a.u = *reinterpret_cast<const uint4*>(A + (size_t)node * 128 + kc * 32 + lg * 8);
    else a.u = make_uint4(0, 0, 0, 0);
    afr[kc] = a.v;
  }
  float pS[4], pD[4];
#pragma unroll
  for (int v = 0; v < 4; v++) { pS[v] = 0.f; pD[v] = 0.f; }
#pragma unroll
  for (int ct = 0; ct < 2; ct++) {
    f32x4 acc = {0.f, 0.f, 0.f, 0.f};
    const ushort* wrow = Wt + (size_t)(ct * 16 + lr) * 128;
#pragma unroll
    for (int kc = 0; kc < 4; kc++) {
      U4B bfr;
      bfr.u = *reinterpret_cast<const uint4*>(wrow + kc * 32 + lg * 8);
      acc = __builtin_amdgcn_mfma_f32_16x16x32_bf16(afr[kc], bfr.v, acc, 0, 0, 0);
    }
    int col = ct * 16 + lr;
    float asw = att_s[col], adw = att_d[col];
#pragma unroll
    for (int v = 0; v < 4; v++) {
      int nrow = row0 + lg * 4 + v;
      if (nrow < M) {
        uint b8 = (uint)__builtin_amdgcn_cvt_pk_fp8_f32(acc[v], acc[v], 0, false);
        hb2[(size_t)nrow * 32 + col] = (uchar)(b8 & 0xFF);
      }
      pS[v] += acc[v] * asw;
      pD[v] += acc[v] * adw;
    }
  }
#pragma unroll
  for (int off = 1; off < 16; off <<= 1) {
#pragma unroll
    for (int v = 0; v < 4; v++) {
      pS[v] += __shfl_xor(pS[v], off, 16);
      pD[v] += __shfl_xor(pD[v], off, 16);
    }
  }
  if (lr == 0) {
#pragma unroll
    for (int v = 0; v < 4; v++) {
      int n2 = row0 + lg * 4 + v;
      if (n2 < M) { asrc[n2] = pS[v]; adst[n2] = pD[v]; }
    }
  }
}

// ---- layer-1 aggregation: wave/dst, 8 slots x 8 lanes x uint4 (full 128B row per edge) ----
__global__ void k_aggr1(const int* __restrict__ offs, const int* __restrict__ ssrc,
                        const uchar* __restrict__ hb, const float* __restrict__ asrc,
                        const float* __restrict__ adst, const float* __restrict__ bias,
                        ushort* __restrict__ outb, int N) {
  int wid = threadIdx.x >> 6, l = threadIdx.x & 63;
  int d = blockIdx.x * 4 + wid;
  if (d >= N) return;
  int slot = l >> 3;       // 0..7 edge slot
  int k = l & 7;           // channel block: ch k*16 .. +15
  int h = k >> 1;          // head of this lane's channels
  float ad = adst[d * 4 + h];
  int beg = offs[d], end = offs[d + 1];
  float a[16] = {};
  float ds = 0.f;
  for (int i = beg; i < end; i += 8) {
    int e = i + slot;
    int ec = min(e, end - 1);
    int s = ssrc[ec];
    float xv = asrc[s * 4 + h] + ad;
    xv = xv > 0.f ? xv : NEG * xv;
    float w = __expf(xv);
    w = (e < end) ? w : 0.f;
    uint4 p = *reinterpret_cast<const uint4*>(hb + (size_t)s * 128 + k * 16);
    uint pu[4] = {p.x, p.y, p.z, p.w};
#pragma unroll
    for (int q = 0; q < 4; q++) {
      f32x2 f0 = __builtin_amdgcn_cvt_pk_f32_fp8(pu[q], false);
      f32x2 f1 = __builtin_amdgcn_cvt_pk_f32_fp8(pu[q], true);
      a[q * 4 + 0] += w * f0.x;
      a[q * 4 + 1] += w * f0.y;
      a[q * 4 + 2] += w * f1.x;
      a[q * 4 + 3] += w * f1.y;
    }
    ds += w;
  }
  int b3 = (l >> 3) & 1, b4 = (l >> 4) & 1, b5 = (l >> 5) & 1;
  float t8[8];
#pragma unroll
  for (int r = 0; r < 8; r++) {
    float send = b3 ? a[r] : a[r + 8];
    float recv = __shfl_xor(send, 8, 64);
    t8[r] = (b3 ? a[r + 8] : a[r]) + recv;
  }
  float t4[4];
#pragma unroll
  for (int r = 0; r < 4; r++) {
    float send = b4 ? t8[r] : t8[r + 4];
    float recv = __shfl_xor(send, 16, 64);
    t4[r] = (b4 ? t8[r + 4] : t8[r]) + recv;
  }
  float t2[2];
#pragma unroll
  for (int r = 0; r < 2; r++) {
    float send = b5 ? t4[r] : t4[r + 2];
    float recv = __shfl_xor(send, 32, 64);
    t2[r] = (b5 ? t4[r + 2] : t4[r]) + recv;
  }
  ds += __shfl_xor(ds, 8, 64);
  ds += __shfl_xor(ds, 16, 64);
  ds += __shfl_xor(ds, 32, 64);
  float inv = 1.f / ds;
  int c0 = k * 16 + b3 * 8 + b4 * 4 + b5 * 2;
  float r0 = t2[0] * inv + bias[c0];
  float r1 = t2[1] * inv + bias[c0 + 1];
  r0 = r0 > 0.f ? r0 : expm1f(r0);
  r1 = r1 > 0.f ? r1 : expm1f(r1);
  *reinterpret_cast<uint*>(outb + (size_t)d * 128 + c0) =
      (uint)f2bf(r0) | ((uint)f2bf(r1) << 16);
}

// ---- layer-2 aggregation: wave/dst, 16 slots x 4 lanes x uint2 (full 32B row per edge) ----
__global__ void k_aggr2(const int* __restrict__ offs, const int* __restrict__ ssrc,
                        const uchar* __restrict__ hb, const float* __restrict__ asrc,
                        const float* __restrict__ adst, const float* __restrict__ bias,
                        float* __restrict__ out, int N) {
  int wid = threadIdx.x >> 6, l = threadIdx.x & 63;
  int d = blockIdx.x * 4 + wid;
  if (d >= N) return;
  int slot = l >> 2;       // 0..15 edge slot
  int k = l & 3;           // channel block: ch k*8 .. +7
  float ad = adst[d];
  int beg = offs[d], end = offs[d + 1];
  float a[8] = {};
  float ds = 0.f;
  for (int i = beg; i < end; i += 16) {
    int e = i + slot;
    int ec = min(e, end - 1);
    int s = ssrc[ec];
    float xv = asrc[s] + ad;
    xv = xv > 0.f ? xv : NEG * xv;
    float w = __expf(xv);
    w = (e < end) ? w : 0.f;
    uint2 p = *reinterpret_cast<const uint2*>(hb + (size_t)s * 32 + k * 8);
    f32x2 f0 = __builtin_amdgcn_cvt_pk_f32_fp8(p.x, false);
    f32x2 f1 = __builtin_amdgcn_cvt_pk_f32_fp8(p.x, true);
    f32x2 f2 = __builtin_amdgcn_cvt_pk_f32_fp8(p.y, false);
    f32x2 f3 = __builtin_amdgcn_cvt_pk_f32_fp8(p.y, true);
    a[0] += w * f0.x; a[1] += w * f0.y; a[2] += w * f1.x; a[3] += w * f1.y;
    a[4] += w * f2.x; a[5] += w * f2.y; a[6] += w * f3.x; a[7] += w * f3.y;
    ds += w;
  }
  int b2 = (l >> 2) & 1, b3 = (l >> 3) & 1, b4 = (l >> 4) & 1;
  float t4[4];
#pragma unroll
  for (int r = 0; r < 4; r++) {
    float send = b2 ? a[r] : a[r + 4];
    float recv = __shfl_xor(send, 4, 64);
    t4[r] = (b2 ? a[r + 4] : a[r]) + recv;
  }
  float t2[2];
#pragma unroll
  for (int r = 0; r < 2; r++) {
    float send = b3 ? t4[r] : t4[r + 2];
    float recv = __shfl_xor(send, 8, 64);
    t2[r] = (b3 ? t4[r + 2] : t4[r]) + recv;
  }
  float send = b4 ? t2[0] : t2[1];
  float recv = __shfl_xor(send, 16, 64);
  float t1 = (b4 ? t2[1] : t2[0]) + recv;
  t1 += __shfl_xor(t1, 32, 64);
  ds += __shfl_xor(ds, 4, 64);
  ds += __shfl_xor(ds, 8, 64);
  ds += __shfl_xor(ds, 16, 64);
  ds += __shfl_xor(ds, 32, 64);
  if (l < 32) {
    int c = k * 8 + b2 * 4 + b3 * 2 + b4;
    float r = t1 / ds + bias[c];
    r = r > 0.f ? r : expm1f(r);
    out[(size_t)d * 32 + c] = r;
  }
}

// ---------------- pool (mean per graph, batch sorted) + FC ----------------
__global__ void k_pool_fc(const float* __restrict__ h2, const int* __restrict__ batch,
                          const float* __restrict__ fcW, const float* __restrict__ fcb,
                          float* __restrict__ out, int N) {
  int g = blockIdx.x;
  int lo = 0, hi = N;
  while (lo < hi) { int mid = (lo + hi) >> 1; if (batch[mid] < g) lo = mid + 1; else hi = mid; }
  int beg = lo;
  hi = N;
  while (lo < hi) { int mid = (lo + hi) >> 1; if (batch[mid] < g + 1) lo = mid + 1; else hi = mid; }
  int end = lo;
  int t = threadIdx.x, c = t & 31, sub = t >> 5;
  float acc = 0.f;
  for (int n = beg + sub; n < end; n += 8) acc += h2[(size_t)n * 32 + c];
  __shared__ float red[8][32];
  __shared__ float pooled[32];
  red[sub][c] = acc;
  __syncthreads();
  if (sub == 0) {
    float s = 0.f;
#pragma unroll
    for (int i = 0; i < 8; i++) s += red[i][c];
    float cnt = (float)(end - beg);
    pooled[c] = s / fmaxf(cnt, 1.f);
  }
  __syncthreads();
  if (t < 16) {
    float r = fcb[t];
#pragma unroll
    for (int cc = 0; cc < 32; cc++) r += pooled[cc] * fcW[cc * 16 + t];
    out[g * 16 + t] = r;
  }
}

// ---------------- host launch ----------------
extern "C" void kernel_launch(void* const* d_in, const int* in_sizes, int n_in,
                              void* d_out, int out_size, void* d_ws, size_t ws_size,
                              hipStream_t stream) {
  const float* x     = (const float*)d_in[0];
  const int*   ei    = (const int*)d_in[1];
  const int*   batch = (const int*)d_in[2];
  const float* nw    = (const float*)d_in[3];
  const float* W1    = (const float*)d_in[4];
  const float* as1w  = (const float*)d_in[5];
  const float* ad1w  = (const float*)d_in[6];
  const float* b1    = (const float*)d_in[7];
  const float* W2    = (const float*)d_in[8];
  const float* as2w  = (const float*)d_in[9];
  const float* ad2w  = (const float*)d_in[10];
  const float* b2    = (const float*)d_in[11];
  const float* fcW   = (const float*)d_in[12];
  const float* fcb   = (const float*)d_in[13];
  float* out = (float*)d_out;

  const int N = in_sizes[0] / 128;
  const int E = in_sizes[1] / 2;
  const int Etot = E + N;
  const int NB = (N + BSZ - 1) >> BSH;

  char* w = (char*)d_ws;
  size_t ofs = 0;
  auto alloc = [&](size_t bytes) {
    char* p = w + ofs;
    ofs += (bytes + 255) & ~(size_t)255;
    return p;
  };
  uchar*  hb1    = (uchar*)alloc((size_t)N * 128);        // fp8 layer-1 features
  ushort* out1b  = (ushort*)alloc((size_t)N * 128 * 2);   // bf16 layer-1 output
  uchar*  hb2    = (uchar*)alloc((size_t)N * 32);         // fp8 layer-2 features
  float*  h2     = (float*)alloc((size_t)N * 32 * 4);     // fp32 layer-2 output
  float*  asrc1  = (float*)alloc((size_t)N * 4 * 4);
  float*  adst1  = (float*)alloc((size_t)N * 4 * 4);
  float*  asrc2  = (float*)alloc((size_t)N * 4);
  float*  adst2  = (float*)alloc((size_t)N * 4);
  ushort* Wt1    = (ushort*)alloc(16384 * 2);
  ushort* Wt2    = (ushort*)alloc(4096 * 2);
  int*    bcur   = (int*)alloc((size_t)NB * 4);
  int*    offs   = (int*)alloc((size_t)(N + 1) * 4);
  uint*   bbuf   = (uint*)alloc((size_t)NB * CAP * 4);
  int*    ssrc   = (int*)alloc((size_t)Etot * 4);

  hipMemsetAsync(bcur, 0, (size_t)NB * 4, stream);

  // binned CSR build (hist+scatter fused; scan folded into k_build) + weight prep
  const int nbin = (Etot + 4095) / 4096;
  k_bin<<<nbin + 80, 256, 0, stream>>>(ei, W1, W2, Wt1, Wt2, E, Etot, NB, nbin, bcur, bbuf);
  k_build<<<NB, BSZ, 0, stream>>>(bbuf, bcur, NB, N, offs, ssrc);

  // layer 1: GEMM+att fused, then aggregation
  k_gemm1<<<(N + 63) / 64, 256, 0, stream>>>(x, Wt1, nw, as1w, ad1w, hb1, asrc1, adst1, N);
  k_aggr1<<<(N + 3) / 4, 256, 0, stream>>>(offs, ssrc, hb1, asrc1, adst1, b1, out1b, N);

  // layer 2
  k_gemm2<<<(N + 63) / 64, 256, 0, stream>>>(out1b, Wt2, as2w, ad2w, hb2, asrc2, adst2, N);
  k_aggr2<<<(N + 3) / 4, 256, 0, stream>>>(offs, ssrc, hb2, asrc2, adst2, b2, h2, N);

  // pool + fc
  k_pool_fc<<<NGRAPH, 256, 0, stream>>>(h2, batch, fcW, fcb, out, N);
}

// Round 9
// 314.290 us; speedup vs baseline: 1.4163x; 1.0368x over previous
//
#include <hip/hip_runtime.h>
#include <cstdint>

#define OUT_C 16
#define NGRAPH 128
#define NEG 0.2f
#define NB_MAX 512      // buckets of 256 dst nodes; N=100K -> 391 buckets
#define BSH 8           // bucket shift
#define BSZ 256         // k_build block size = bucket size
#define CAP 8192        // bbuf slots per bucket (expected max ~4600)

typedef unsigned int uint;
typedef unsigned short ushort;
typedef unsigned char uchar;
typedef __attribute__((ext_vector_type(8))) short bf16x8;
typedef __attribute__((ext_vector_type(4))) float f32x4;
typedef __attribute__((ext_vector_type(2))) float f32x2;

union U4B { uint4 u; bf16x8 v; };

__device__ __forceinline__ ushort f2bf(float f) {
  uint u = __float_as_uint(f);
  uint r = (u + 0x7FFF + ((u >> 16) & 1)) >> 16;   // RNE
  return (ushort)r;
}

__device__ __forceinline__ int wave_incl_scan_i(int v) {
  int lane = threadIdx.x & 63;
#pragma unroll
  for (int off = 1; off < 64; off <<= 1) {
    int u = __shfl_up(v, off, 64);
    if (lane >= off) v += u;
  }
  return v;
}

// ---------------- k_bin: per-block LDS hist -> bucket alloc -> scatter; + weight prep ----------------
__global__ void k_bin(const int* __restrict__ ei,
                      const float* __restrict__ W1, const float* __restrict__ W2,
                      ushort* __restrict__ Wt1, ushort* __restrict__ Wt2,
                      int E, int Etot, int NB, int nbin,
                      int* __restrict__ bcur, uint* __restrict__ bbuf) {
  if (blockIdx.x >= nbin) {
    int t2 = (blockIdx.x - nbin) * 256 + threadIdx.x;
    if (t2 < 16384) {
      int n = t2 >> 7, k = t2 & 127;
      Wt1[t2] = f2bf(W1[k * 128 + n]);
    } else {
      int u = t2 - 16384;
      int n = u >> 7, k = u & 127;
      Wt2[u] = f2bf(W2[k * 32 + n]);
    }
    return;
  }
  __shared__ int h[NB_MAX];
  __shared__ int baseo[NB_MAX];
  int t = threadIdx.x;
  for (int b = t; b < NB; b += 256) h[b] = 0;
  __syncthreads();
  int cbase = blockIdx.x * 4096;
  int cend = min(cbase + 4096, Etot);
  for (int e = cbase + t; e < cend; e += 256) {
    int d = (e < E) ? ei[E + e] : (e - E);
    atomicAdd(&h[d >> BSH], 1);
  }
  __syncthreads();
  for (int b = t; b < NB; b += 256) {
    int c = h[b];
    baseo[b] = c ? atomicAdd(&bcur[b], c) : 0;
    h[b] = 0;
  }
  __syncthreads();
  for (int e = cbase + t; e < cend; e += 256) {
    int s, d;
    if (e < E) { s = ei[e]; d = ei[E + e]; } else { s = e - E; d = s; }
    int b = d >> BSH;
    int r = atomicAdd(&h[b], 1);
    bbuf[(size_t)b * CAP + baseo[b] + r] = ((uint)(d & (BSZ - 1)) << 17) | (uint)s;
  }
}

// ---------------- k_bg: blocks [0,NB) = CSR build; blocks [NB,..) = GEMM1+att1 ----------------
// build: parallel scan of bcur -> bucket starts; degree hist -> offs; rank+scatter -> ssrc.
// gemm1 (operand-swapped MFMA): D[channel][node]; lane owns 4 consecutive channels of 1 node.
__global__ void k_bg(const uint* __restrict__ bbuf, const int* __restrict__ bcur,
                     int NB, int N, int* __restrict__ offs, int* __restrict__ ssrc,
                     const float* __restrict__ x, const ushort* __restrict__ Wt,
                     const float* __restrict__ nw, const float* __restrict__ att_s,
                     const float* __restrict__ att_d, uchar* __restrict__ hb1,
                     float* __restrict__ asrc, float* __restrict__ adst) {
  __shared__ int sst[NB_MAX + 1];
  __shared__ int wsum2[4];
  __shared__ int deg[BSZ];
  if (blockIdx.x < (uint)NB) {
    int t = threadIdx.x, lane = t & 63, wid = t >> 6;
    int v0 = (2 * t < NB) ? bcur[2 * t] : 0;
    int v1 = (2 * t + 1 < NB) ? bcur[2 * t + 1] : 0;
    int s = v0 + v1;
    int sv = wave_incl_scan_i(s);
    if (lane == 63) wsum2[wid] = sv;
    deg[t] = 0;
    __syncthreads();
    if (t == 0) {
      int r = 0;
#pragma unroll
      for (int k = 0; k < 4; k++) { int x2 = wsum2[k]; wsum2[k] = r; r += x2; }
    }
    __syncthreads();
    int excl = wsum2[wid] + sv - s;
    sst[2 * t] = excl;
    sst[2 * t + 1] = excl + v0;
    if (t == 255) sst[512] = excl + v0 + v1;
    __syncthreads();
    int b = blockIdx.x;
    int ebeg = sst[b], eend = sst[b + 1];
    int cnt = eend - ebeg;
    for (int i = t; i < cnt; i += BSZ)
      atomicAdd(&deg[bbuf[(size_t)b * CAP + i] >> 17], 1);
    __syncthreads();
    int v = deg[t];
    int sv2 = wave_incl_scan_i(v);
    if (lane == 63) wsum2[wid] = sv2;
    __syncthreads();
    if (t == 0) {
      int r = 0;
#pragma unroll
      for (int k = 0; k < 4; k++) { int x2 = wsum2[k]; wsum2[k] = r; r += x2; }
    }
    __syncthreads();
    int excl2 = wsum2[wid] + sv2 - v;
    int node = (b << BSH) + t;
    if (node < N) offs[node] = ebeg + excl2;
    if (b == 0 && t == 0) offs[N] = sst[512];
    __syncthreads();
    deg[t] = excl2;
    __syncthreads();
    for (int i = t; i < cnt; i += BSZ) {
      uint rec = bbuf[(size_t)b * CAP + i];
      int r = atomicAdd(&deg[rec >> 17], 1);
      ssrc[ebeg + r] = (int)(rec & 0x1FFFF);
    }
    return;
  }
  // ---- gemm1 path ----
  int bid = blockIdx.x - NB;
  int wv = threadIdx.x >> 6, l = threadIdx.x & 63;
  int lg = l >> 4, lr = l & 15;
  int row0 = bid * 64 + wv * 16;
  int node = row0 + lr;
  bool valid = node < N;
  float sc = valid ? nw[node] : 0.f;
  bf16x8 xfr[4];
  const float* xr = x + (size_t)node * 128;
#pragma unroll
  for (int kc = 0; kc < 4; kc++) {
    float v[8];
    if (valid) {
      float4 q0 = *reinterpret_cast<const float4*>(xr + kc * 32 + lg * 8);
      float4 q1 = *reinterpret_cast<const float4*>(xr + kc * 32 + lg * 8 + 4);
      v[0] = q0.x; v[1] = q0.y; v[2] = q0.z; v[3] = q0.w;
      v[4] = q1.x; v[5] = q1.y; v[6] = q1.z; v[7] = q1.w;
    } else {
#pragma unroll
      for (int j = 0; j < 8; j++) v[j] = 0.f;
    }
    U4B a;
    uint pk0 = (uint)f2bf(v[0] * sc) | ((uint)f2bf(v[1] * sc) << 16);
    uint pk1 = (uint)f2bf(v[2] * sc) | ((uint)f2bf(v[3] * sc) << 16);
    uint pk2 = (uint)f2bf(v[4] * sc) | ((uint)f2bf(v[5] * sc) << 16);
    uint pk3 = (uint)f2bf(v[6] * sc) | ((uint)f2bf(v[7] * sc) << 16);
    a.u = make_uint4(pk0, pk1, pk2, pk3);
    xfr[kc] = a.v;
  }
  float pS[4] = {}, pD[4] = {};
#pragma unroll
  for (int ct = 0; ct < 8; ct++) {
    f32x4 acc = {0.f, 0.f, 0.f, 0.f};
    const ushort* wrow = Wt + (size_t)(ct * 16 + lr) * 128;
#pragma unroll
    for (int kc = 0; kc < 4; kc++) {
      U4B bfr;
      bfr.u = *reinterpret_cast<const uint4*>(wrow + kc * 32 + lg * 8);
      // swapped: W-frag as A, x-frag as B -> D[channel][node]
      acc = __builtin_amdgcn_mfma_f32_16x16x32_bf16(bfr.v, xfr[kc], acc, 0, 0, 0);
    }
    int c0 = ct * 16 + lg * 4;
    if (valid) {
      uint u8 = (uint)__builtin_amdgcn_cvt_pk_fp8_f32(acc[0], acc[1], 0, false);
      u8 = (uint)__builtin_amdgcn_cvt_pk_fp8_f32(acc[2], acc[3], u8, true);
      *reinterpret_cast<uint*>(hb1 + (size_t)node * 128 + c0) = u8;
    }
    float4 as4 = *reinterpret_cast<const float4*>(att_s + c0);
    float4 ad4 = *reinterpret_cast<const float4*>(att_d + c0);
    int h = ct >> 1;
    pS[h] += acc[0] * as4.x + acc[1] * as4.y + acc[2] * as4.z + acc[3] * as4.w;
    pD[h] += acc[0] * ad4.x + acc[1] * ad4.y + acc[2] * ad4.z + acc[3] * ad4.w;
  }
#pragma unroll
  for (int off = 16; off < 64; off <<= 1) {
#pragma unroll
    for (int h = 0; h < 4; h++) {
      pS[h] += __shfl_xor(pS[h], off, 64);
      pD[h] += __shfl_xor(pD[h], off, 64);
    }
  }
  if (lg == 0 && valid) {
    *reinterpret_cast<float4*>(asrc + node * 4) = make_float4(pS[0], pS[1], pS[2], pS[3]);
    *reinterpret_cast<float4*>(adst + node * 4) = make_float4(pD[0], pD[1], pD[2], pD[3]);
  }
}

// ---------------- GEMM2 (operand-swapped MFMA) + fused att2: hb2 fp8[M][32] ----------------
__global__ void k_gemm2(const ushort* __restrict__ A, const ushort* __restrict__ Wt,
                        const float* __restrict__ att_s, const float* __restrict__ att_d,
                        uchar* __restrict__ hb2, float* __restrict__ asrc,
                        float* __restrict__ adst, int M) {
  int wv = threadIdx.x >> 6, l = threadIdx.x & 63;
  int lg = l >> 4, lr = l & 15;
  int row0 = blockIdx.x * 64 + wv * 16;
  int node = row0 + lr;
  bool valid = node < M;
  bf16x8 afr[4];
#pragma unroll
  for (int kc = 0; kc < 4; kc++) {
    U4B a;
    if (valid) a.u = *reinterpret_cast<const uint4*>(A + (size_t)node * 128 + kc * 32 + lg * 8);
    else a.u = make_uint4(0, 0, 0, 0);
    afr[kc] = a.v;
  }
  float pS = 0.f, pD = 0.f;
#pragma unroll
  for (int ct = 0; ct < 2; ct++) {
    f32x4 acc = {0.f, 0.f, 0.f, 0.f};
    const ushort* wrow = Wt + (size_t)(ct * 16 + lr) * 128;
#pragma unroll
    for (int kc = 0; kc < 4; kc++) {
      U4B bfr;
      bfr.u = *reinterpret_cast<const uint4*>(wrow + kc * 32 + lg * 8);
      acc = __builtin_amdgcn_mfma_f32_16x16x32_bf16(bfr.v, afr[kc], acc, 0, 0, 0);
    }
    int c0 = ct * 16 + lg * 4;
    if (valid) {
      uint u8 = (uint)__builtin_amdgcn_cvt_pk_fp8_f32(acc[0], acc[1], 0, false);
      u8 = (uint)__builtin_amdgcn_cvt_pk_fp8_f32(acc[2], acc[3], u8, true);
      *reinterpret_cast<uint*>(hb2 + (size_t)node * 32 + c0) = u8;
    }
    float4 as4 = *reinterpret_cast<const float4*>(att_s + c0);
    float4 ad4 = *reinterpret_cast<const float4*>(att_d + c0);
    pS += acc[0] * as4.x + acc[1] * as4.y + acc[2] * as4.z + acc[3] * as4.w;
    pD += acc[0] * ad4.x + acc[1] * ad4.y + acc[2] * ad4.z + acc[3] * ad4.w;
  }
#pragma unroll
  for (int off = 16; off < 64; off <<= 1) {
    pS += __shfl_xor(pS, off, 64);
    pD += __shfl_xor(pD, off, 64);
  }
  if (lg == 0 && valid) { asrc[node] = pS; adst[node] = pD; }
}

// ---- layer-1 aggregation: wave/dst, 8 slots x 8 lanes x uint4 (full 128B row per edge) ----
__global__ void k_aggr1(const int* __restrict__ offs, const int* __restrict__ ssrc,
                        const uchar* __restrict__ hb, const float* __restrict__ asrc,
                        const float* __restrict__ adst, const float* __restrict__ bias,
                        ushort* __restrict__ outb, int N) {
  int wid = threadIdx.x >> 6, l = threadIdx.x & 63;
  int d = blockIdx.x * 4 + wid;
  if (d >= N) return;
  int slot = l >> 3;       // 0..7 edge slot
  int k = l & 7;           // channel block: ch k*16 .. +15
  int h = k >> 1;          // head of this lane's channels
  float ad = adst[d * 4 + h];
  int beg = offs[d], end = offs[d + 1];
  float a[16] = {};
  float ds = 0.f;
  for (int i = beg; i < end; i += 8) {
    int e = i + slot;
    int ec = min(e, end - 1);
    int s = ssrc[ec];
    float xv = asrc[s * 4 + h] + ad;
    xv = xv > 0.f ? xv : NEG * xv;
    float w = __expf(xv);
    w = (e < end) ? w : 0.f;
    uint4 p = *reinterpret_cast<const uint4*>(hb + (size_t)s * 128 + k * 16);
    uint pu[4] = {p.x, p.y, p.z, p.w};
#pragma unroll
    for (int q = 0; q < 4; q++) {
      f32x2 f0 = __builtin_amdgcn_cvt_pk_f32_fp8(pu[q], false);
      f32x2 f1 = __builtin_amdgcn_cvt_pk_f32_fp8(pu[q], true);
      a[q * 4 + 0] += w * f0.x;
      a[q * 4 + 1] += w * f0.y;
      a[q * 4 + 2] += w * f1.x;
      a[q * 4 + 3] += w * f1.y;
    }
    ds += w;
  }
  int b3 = (l >> 3) & 1, b4 = (l >> 4) & 1, b5 = (l >> 5) & 1;
  float t8[8];
#pragma unroll
  for (int r = 0; r < 8; r++) {
    float send = b3 ? a[r] : a[r + 8];
    float recv = __shfl_xor(send, 8, 64);
    t8[r] = (b3 ? a[r + 8] : a[r]) + recv;
  }
  float t4[4];
#pragma unroll
  for (int r = 0; r < 4; r++) {
    float send = b4 ? t8[r] : t8[r + 4];
    float recv = __shfl_xor(send, 16, 64);
    t4[r] = (b4 ? t8[r + 4] : t8[r]) + recv;
  }
  float t2[2];
#pragma unroll
  for (int r = 0; r < 2; r++) {
    float send = b5 ? t4[r] : t4[r + 2];
    float recv = __shfl_xor(send, 32, 64);
    t2[r] = (b5 ? t4[r + 2] : t4[r]) + recv;
  }
  ds += __shfl_xor(ds, 8, 64);
  ds += __shfl_xor(ds, 16, 64);
  ds += __shfl_xor(ds, 32, 64);
  float inv = 1.f / ds;
  int c0 = k * 16 + b3 * 8 + b4 * 4 + b5 * 2;
  float r0 = t2[0] * inv + bias[c0];
  float r1 = t2[1] * inv + bias[c0 + 1];
  r0 = r0 > 0.f ? r0 : expm1f(r0);
  r1 = r1 > 0.f ? r1 : expm1f(r1);
  *reinterpret_cast<uint*>(outb + (size_t)d * 128 + c0) =
      (uint)f2bf(r0) | ((uint)f2bf(r1) << 16);
}

// ---- layer-2 aggregation: wave/dst, 16 slots x 4 lanes x uint2 (full 32B row per edge) ----
__global__ void k_aggr2(const int* __restrict__ offs, const int* __restrict__ ssrc,
                        const uchar* __restrict__ hb, const float* __restrict__ asrc,
                        const float* __restrict__ adst, const float* __restrict__ bias,
                        float* __restrict__ out, int N) {
  int wid = threadIdx.x >> 6, l = threadIdx.x & 63;
  int d = blockIdx.x * 4 + wid;
  if (d >= N) return;
  int slot = l >> 2;       // 0..15 edge slot
  int k = l & 3;           // channel block: ch k*8 .. +7
  float ad = adst[d];
  int beg = offs[d], end = offs[d + 1];
  float a[8] = {};
  float ds = 0.f;
  for (int i = beg; i < end; i += 16) {
    int e = i + slot;
    int ec = min(e, end - 1);
    int s = ssrc[ec];
    float xv = asrc[s] + ad;
    xv = xv > 0.f ? xv : NEG * xv;
    float w = __expf(xv);
    w = (e < end) ? w : 0.f;
    uint2 p = *reinterpret_cast<const uint2*>(hb + (size_t)s * 32 + k * 8);
    f32x2 f0 = __builtin_amdgcn_cvt_pk_f32_fp8(p.x, false);
    f32x2 f1 = __builtin_amdgcn_cvt_pk_f32_fp8(p.x, true);
    f32x2 f2 = __builtin_amdgcn_cvt_pk_f32_fp8(p.y, false);
    f32x2 f3 = __builtin_amdgcn_cvt_pk_f32_fp8(p.y, true);
    a[0] += w * f0.x; a[1] += w * f0.y; a[2] += w * f1.x; a[3] += w * f1.y;
    a[4] += w * f2.x; a[5] += w * f2.y; a[6] += w * f3.x; a[7] += w * f3.y;
    ds += w;
  }
  int b2 = (l >> 2) & 1, b3 = (l >> 3) & 1, b4 = (l >> 4) & 1;
  float t4[4];
#pragma unroll
  for (int r = 0; r < 4; r++) {
    float send = b2 ? a[r] : a[r + 4];
    float recv = __shfl_xor(send, 4, 64);
    t4[r] = (b2 ? a[r + 4] : a[r]) + recv;
  }
  float t2[2];
#pragma unroll
  for (int r = 0; r < 2; r++) {
    float send = b3 ? t4[r] : t4[r + 2];
    float recv = __shfl_xor(send, 8, 64);
    t2[r] = (b3 ? t4[r + 2] : t4[r]) + recv;
  }
  float send = b4 ? t2[0] : t2[1];
  float recv = __shfl_xor(send, 16, 64);
  float t1 = (b4 ? t2[1] : t2[0]) + recv;
  t1 += __shfl_xor(t1, 32, 64);
  ds += __shfl_xor(ds, 4, 64);
  ds += __shfl_xor(ds, 8, 64);
  ds += __shfl_xor(ds, 16, 64);
  ds += __shfl_xor(ds, 32, 64);
  if (l < 32) {
    int c = k * 8 + b2 * 4 + b3 * 2 + b4;
    float r = t1 / ds + bias[c];
    r = r > 0.f ? r : expm1f(r);
    out[(size_t)d * 32 + c] = r;
  }
}

// ---------------- pool (mean per graph, batch sorted) + FC ----------------
__global__ void k_pool_fc(const float* __restrict__ h2, const int* __restrict__ batch,
                          const float* __restrict__ fcW, const float* __restrict__ fcb,
                          float* __restrict__ out, int N) {
  int g = blockIdx.x;
  int lo = 0, hi = N;
  while (lo < hi) { int mid = (lo + hi) >> 1; if (batch[mid] < g) lo = mid + 1; else hi = mid; }
  int beg = lo;
  hi = N;
  while (lo < hi) { int mid = (lo + hi) >> 1; if (batch[mid] < g + 1) lo = mid + 1; else hi = mid; }
  int end = lo;
  int t = threadIdx.x, c = t & 31, sub = t >> 5;
  float acc = 0.f;
  for (int n = beg + sub; n < end; n += 8) acc += h2[(size_t)n * 32 + c];
  __shared__ float red[8][32];
  __shared__ float pooled[32];
  red[sub][c] = acc;
  __syncthreads();
  if (sub == 0) {
    float s = 0.f;
#pragma unroll
    for (int i = 0; i < 8; i++) s += red[i][c];
    float cnt = (float)(end - beg);
    pooled[c] = s / fmaxf(cnt, 1.f);
  }
  __syncthreads();
  if (t < 16) {
    float r = fcb[t];
#pragma unroll
    for (int cc = 0; cc < 32; cc++) r += pooled[cc] * fcW[cc * 16 + t];
    out[g * 16 + t] = r;
  }
}

// ---------------- host launch ----------------
extern "C" void kernel_launch(void* const* d_in, const int* in_sizes, int n_in,
                              void* d_out, int out_size, void* d_ws, size_t ws_size,
                              hipStream_t stream) {
  const float* x     = (const float*)d_in[0];
  const int*   ei    = (const int*)d_in[1];
  const int*   batch = (const int*)d_in[2];
  const float* nw    = (const float*)d_in[3];
  const float* W1    = (const float*)d_in[4];
  const float* as1w  = (const float*)d_in[5];
  const float* ad1w  = (const float*)d_in[6];
  const float* b1    = (const float*)d_in[7];
  const float* W2    = (const float*)d_in[8];
  const float* as2w  = (const float*)d_in[9];
  const float* ad2w  = (const float*)d_in[10];
  const float* b2    = (const float*)d_in[11];
  const float* fcW   = (const float*)d_in[12];
  const float* fcb   = (const float*)d_in[13];
  float* out = (float*)d_out;

  const int N = in_sizes[0] / 128;
  const int E = in_sizes[1] / 2;
  const int Etot = E + N;
  const int NB = (N + BSZ - 1) >> BSH;

  char* w = (char*)d_ws;
  size_t ofs = 0;
  auto alloc = [&](size_t bytes) {
    char* p = w + ofs;
    ofs += (bytes + 255) & ~(size_t)255;
    return p;
  };
  uchar*  hb1    = (uchar*)alloc((size_t)N * 128);        // fp8 layer-1 features
  ushort* out1b  = (ushort*)alloc((size_t)N * 128 * 2);   // bf16 layer-1 output
  uchar*  hb2    = (uchar*)alloc((size_t)N * 32);         // fp8 layer-2 features
  float*  h2     = (float*)alloc((size_t)N * 32 * 4);     // fp32 layer-2 output
  float*  asrc1  = (float*)alloc((size_t)N * 4 * 4);
  float*  adst1  = (float*)alloc((size_t)N * 4 * 4);
  float*  asrc2  = (float*)alloc((size_t)N * 4);
  float*  adst2  = (float*)alloc((size_t)N * 4);
  ushort* Wt1    = (ushort*)alloc(16384 * 2);
  ushort* Wt2    = (ushort*)alloc(4096 * 2);
  int*    bcur   = (int*)alloc((size_t)NB * 4);
  int*    offs   = (int*)alloc((size_t)(N + 1) * 4);
  uint*   bbuf   = (uint*)alloc((size_t)NB * CAP * 4);
  int*    ssrc   = (int*)alloc((size_t)Etot * 4);

  hipMemsetAsync(bcur, 0, (size_t)NB * 4, stream);

  // binned CSR: hist+scatter (+weight prep folded in)
  const int nbin = (Etot + 4095) / 4096;
  k_bin<<<nbin + 80, 256, 0, stream>>>(ei, W1, W2, Wt1, Wt2, E, Etot, NB, nbin, bcur, bbuf);

  // build ‖ gemm1 (independent): blocks [0,NB) build CSR, rest run GEMM1+att1
  const int ngemm1 = (N + 63) / 64;
  k_bg<<<NB + ngemm1, 256, 0, stream>>>(bbuf, bcur, NB, N, offs, ssrc,
                                        x, Wt1, nw, as1w, ad1w, hb1, asrc1, adst1);

  // layer-1 aggregation
  k_aggr1<<<(N + 3) / 4, 256, 0, stream>>>(offs, ssrc, hb1, asrc1, adst1, b1, out1b, N);

  // layer 2
  k_gemm2<<<(N + 63) / 64, 256, 0, stream>>>(out1b, Wt2, as2w, ad2w, hb2, asrc2, adst2, N);
  k_aggr2<<<(N + 3) / 4, 256, 0, stream>>>(offs, ssrc, hb2, asrc2, adst2, b2, h2, N);

  // pool + fc
  k_pool_fc<<<NGRAPH, 256, 0, stream>>>(h2, batch, fcW, fcb, out, N);
}